// Round 1
// baseline (684.266 us; speedup 1.0000x reference)
//
#include <hip/hip_runtime.h>

#define D_FEAT 256
#define NEG_SLOPE 0.2f

// Monotone float -> uint map (order-preserving for all finite floats and +-inf)
__device__ __forceinline__ unsigned fmap(float f) {
    unsigned u = __float_as_uint(f);
    return (u & 0x80000000u) ? ~u : (u | 0x80000000u);
}
__device__ __forceinline__ float funmap(unsigned u) {
    return __uint_as_float((u & 0x80000000u) ? (u ^ 0x80000000u) : ~u);
}

__global__ void k_init(unsigned* m_u, float* ssum, float* numer, int* rA, int* rB,
                       unsigned* pooled_u, unsigned* sc, int n) {
    int i = blockIdx.x * blockDim.x + threadIdx.x;
    if (i < n) { m_u[i] = 0u; ssum[i] = 0.f; numer[i] = 0.f; rA[i] = 0; rB[i] = 0; }
    if (i < D_FEAT) pooled_u[i] = 0u;
    if (i == 0) { sc[0] = 0u; ((float*)sc)[1] = 0.f; sc[2] = 0xFFFFFFFFu; }
}

// One wave (64 lanes) per node: xl[i] = x[i,:]·w_l, xr[i] = x[i,:]·w_r  (float4 loads)
__global__ void k_dots(const float* __restrict__ x, const float* __restrict__ w_l,
                       const float* __restrict__ w_r, float* __restrict__ xl,
                       float* __restrict__ xr, int n) {
    int wave = (int)((blockIdx.x * blockDim.x + threadIdx.x) >> 6);
    int lane = threadIdx.x & 63;
    if (wave >= n) return;
    const float4* xv = (const float4*)(x + (size_t)wave * D_FEAT);
    const float4* wl = (const float4*)w_l;
    const float4* wr = (const float4*)w_r;
    float4 v = xv[lane];
    float4 a = wl[lane];
    float4 b = wr[lane];
    float sl = v.x * a.x + v.y * a.y + v.z * a.z + v.w * a.w;
    float sr = v.x * b.x + v.y * b.y + v.z * b.z + v.w * b.w;
    #pragma unroll
    for (int o = 32; o; o >>= 1) { sl += __shfl_xor(sl, o); sr += __shfl_xor(sr, o); }
    if (lane == 0) { xl[wave] = sl; xr[wave] = sr; }
}

__device__ __forceinline__ float edge_e(int s, int d,
                                        const float* __restrict__ xl,
                                        const float* __restrict__ xr,
                                        const float* __restrict__ pos,
                                        float we0, float we1, float we2, float at) {
    float ea = (pos[3 * d + 0] - pos[3 * s + 0]) * we0
             + (pos[3 * d + 1] - pos[3 * s + 1]) * we1
             + (pos[3 * d + 2] - pos[3 * s + 2]) * we2;
    float msg = xl[s] + xr[d] + ea;
    float lr = (msg >= 0.f) ? msg : NEG_SLOPE * msg;
    return lr * at;
}

__global__ void k_edge_max(const int* __restrict__ src, const int* __restrict__ dst,
                           const float* __restrict__ xl, const float* __restrict__ xr,
                           const float* __restrict__ pos, const float* __restrict__ w_e,
                           const float* __restrict__ att, unsigned* m_u, int E) {
    int i = blockIdx.x * blockDim.x + threadIdx.x;
    if (i >= E) return;
    int s = src[i], d = dst[i];
    float e = edge_e(s, d, xl, xr, pos, w_e[0], w_e[1], w_e[2], att[0]);
    atomicMax(&m_u[d], fmap(e));
}

__global__ void k_edge_sum(const int* __restrict__ src, const int* __restrict__ dst,
                           const float* __restrict__ xl, const float* __restrict__ xr,
                           const float* __restrict__ pos, const float* __restrict__ w_e,
                           const float* __restrict__ att, const unsigned* __restrict__ m_u,
                           float* ssum, float* numer, int E) {
    int i = blockIdx.x * blockDim.x + threadIdx.x;
    if (i >= E) return;
    int s = src[i], d = dst[i];
    float e = edge_e(s, d, xl, xr, pos, w_e[0], w_e[1], w_e[2], att[0]);
    float mv = funmap(m_u[d]);
    float ex = expf(e - mv);
    atomicAdd(&ssum[d], ex);
    atomicAdd(&numer[d], ex * xl[s]);
}

// logits[i] = numer/(s+1e-16) + bias; wave-reduce max(mapped) -> sc[0]
__global__ void k_logits(const float* __restrict__ numer, const float* __restrict__ ssum,
                         const float* __restrict__ bias, float* __restrict__ logits,
                         unsigned* sc, int n) {
    int i = blockIdx.x * blockDim.x + threadIdx.x;
    unsigned mu = 0u;
    if (i < n) {
        float lg = numer[i] / (ssum[i] + 1e-16f) + bias[0];
        logits[i] = lg;
        mu = fmap(lg);
    }
    #pragma unroll
    for (int o = 32; o; o >>= 1) { unsigned t = __shfl_xor(mu, o); mu = (t > mu) ? t : mu; }
    if ((threadIdx.x & 63) == 0) atomicMax(&sc[0], mu);
}

// sum of exp(l - max) -> sc[1]; first index attaining max -> sc[2]
__global__ void k_sumarg(const float* __restrict__ logits, unsigned* sc, int n) {
    int i = blockIdx.x * blockDim.x + threadIdx.x;
    unsigned gmax_u = sc[0];
    float gmax = funmap(gmax_u);
    float ex = 0.f;
    if (i < n) {
        float lg = logits[i];
        ex = expf(lg - gmax);
        if (fmap(lg) == gmax_u) atomicMin(&sc[2], (unsigned)i);
    }
    #pragma unroll
    for (int o = 32; o; o >>= 1) ex += __shfl_xor(ex, o);
    if ((threadIdx.x & 63) == 0) atomicAdd((float*)&sc[1], ex);
}

__global__ void k_score(const float* __restrict__ logits, const unsigned* __restrict__ sc,
                        float* __restrict__ out, int* rA, int n) {
    int i = blockIdx.x * blockDim.x + threadIdx.x;
    if (i >= n) return;
    float gmax = funmap(sc[0]);
    float gsum = ((const float*)sc)[1];
    out[i] = expf(logits[i] - gmax) / gsum;
    if (i == (int)sc[2]) rA[i] = 1;
}

__global__ void k_copy(const int* __restrict__ cur, int* __restrict__ nxt, int n) {
    int i = blockIdx.x * blockDim.x + threadIdx.x;
    if (i < n) nxt[i] = cur[i];
}

__global__ void k_bfs(const int* __restrict__ src, const int* __restrict__ dst,
                      const int* __restrict__ cur, int* __restrict__ nxt, int E) {
    int i = blockIdx.x * blockDim.x + threadIdx.x;
    if (i >= E) return;
    if (cur[src[i]]) nxt[dst[i]] = 1;
}

// 256 threads = 256 columns; block-strided rows; coalesced x reads
__global__ void k_pool(const float* __restrict__ x, const int* __restrict__ reach,
                       unsigned* pooled_u, int n) {
    int t = threadIdx.x;
    float local = -INFINITY;
    for (int node = blockIdx.x; node < n; node += gridDim.x) {
        if (reach[node]) local = fmaxf(local, x[(size_t)node * D_FEAT + t]);
    }
    atomicMax(&pooled_u[t], fmap(local));
}

__global__ void k_poolwrite(const unsigned* __restrict__ pooled_u, float* __restrict__ out, int n) {
    int t = threadIdx.x;
    out[n + t] = funmap(pooled_u[t]);
}

extern "C" void kernel_launch(void* const* d_in, const int* in_sizes, int n_in,
                              void* d_out, int out_size, void* d_ws, size_t ws_size,
                              hipStream_t stream) {
    const float* x    = (const float*)d_in[0];
    const float* pos  = (const float*)d_in[1];
    const float* w_l  = (const float*)d_in[2];
    const float* w_r  = (const float*)d_in[3];
    const float* w_e  = (const float*)d_in[4];
    const float* att  = (const float*)d_in[5];
    const float* bias = (const float*)d_in[6];
    const int*   ei   = (const int*)d_in[7];

    const int n = in_sizes[0] / D_FEAT;     // 100000
    const int E = in_sizes[7] / 2;          // 3200000
    const int* src = ei;
    const int* dst = ei + E;

    float* ws = (float*)d_ws;
    float*    xl       = ws;
    float*    xr       = ws + (size_t)n;
    unsigned* m_u      = (unsigned*)(ws + 2 * (size_t)n);
    float*    ssum     = ws + 3 * (size_t)n;
    float*    numer    = ws + 4 * (size_t)n;
    float*    logits   = ws + 5 * (size_t)n;
    int*      rA       = (int*)(ws + 6 * (size_t)n);
    int*      rB       = (int*)(ws + 7 * (size_t)n);
    unsigned* pooled_u = (unsigned*)(ws + 8 * (size_t)n);
    unsigned* sc       = (unsigned*)(ws + 8 * (size_t)n + D_FEAT);

    float* out = (float*)d_out;

    const int B = 256;
    const int gN = (n + B - 1) / B;
    const int gE = (E + B - 1) / B;
    const int gD = (n + 3) / 4;   // 4 waves/block, 1 wave/node

    k_init<<<gN, B, 0, stream>>>(m_u, ssum, numer, rA, rB, pooled_u, sc, n);
    k_dots<<<gD, B, 0, stream>>>(x, w_l, w_r, xl, xr, n);
    k_edge_max<<<gE, B, 0, stream>>>(src, dst, xl, xr, pos, w_e, att, m_u, E);
    k_edge_sum<<<gE, B, 0, stream>>>(src, dst, xl, xr, pos, w_e, att, m_u, ssum, numer, E);
    k_logits<<<gN, B, 0, stream>>>(numer, ssum, bias, logits, sc, n);
    k_sumarg<<<gN, B, 0, stream>>>(logits, sc, n);
    k_score<<<gN, B, 0, stream>>>(logits, sc, out, rA, n);

    int* cur = rA;
    int* nxt = rB;
    for (int it = 0; it < 5; ++it) {
        k_copy<<<gN, B, 0, stream>>>(cur, nxt, n);
        k_bfs<<<gE, B, 0, stream>>>(src, dst, cur, nxt, E);
        int* t = cur; cur = nxt; nxt = t;
    }

    k_pool<<<2048, B, 0, stream>>>(x, cur, pooled_u, n);
    k_poolwrite<<<1, B, 0, stream>>>(pooled_u, out, n);
}

// Round 2
// 574.858 us; speedup vs baseline: 1.1903x; 1.1903x over previous
//
#include <hip/hip_runtime.h>

#define D_FEAT 256
#define NEG_SLOPE 0.2f

// Monotone float -> uint map (order-preserving, includes +-inf)
__device__ __forceinline__ unsigned fmap(float f) {
    unsigned u = __float_as_uint(f);
    return (u & 0x80000000u) ? ~u : (u | 0x80000000u);
}
__device__ __forceinline__ float funmap(unsigned u) {
    return __uint_as_float((u & 0x80000000u) ? (u ^ 0x80000000u) : ~u);
}

// sc layout (unsigned/float slots):
// [0] gmax_u  [1] gsum(f32)  [2] argmin  [3] M(f32)
// [4] maxA_u  [5] maxB_u     [6] minA_u  [7] minB_u

__global__ void k_init(float2* NS, int* rA, int* rB, unsigned* pooled_u, unsigned* sc, int n) {
    int i = blockIdx.x * blockDim.x + threadIdx.x;
    if (i < n) { NS[i] = make_float2(0.f, 0.f); rA[i] = 0; rB[i] = 0; }
    if (i < D_FEAT) pooled_u[i] = 0u;
    if (i == 0) {
        sc[0] = 0u; ((float*)sc)[1] = 0.f; sc[2] = 0xFFFFFFFFu;
        sc[4] = 0u; sc[5] = 0u; sc[6] = 0xFFFFFFFFu; sc[7] = 0xFFFFFFFFu;
    }
}

// One wave per node: xl[i] = x[i,:]·w_l, xr[i] = x[i,:]·w_r
__global__ void k_dots(const float* __restrict__ x, const float* __restrict__ w_l,
                       const float* __restrict__ w_r, float* __restrict__ xl,
                       float* __restrict__ xr, int n) {
    int wave = (int)((blockIdx.x * blockDim.x + threadIdx.x) >> 6);
    int lane = threadIdx.x & 63;
    if (wave >= n) return;
    const float4* xv = (const float4*)(x + (size_t)wave * D_FEAT);
    float4 v = xv[lane];
    float4 a = ((const float4*)w_l)[lane];
    float4 b = ((const float4*)w_r)[lane];
    float sl = v.x * a.x + v.y * a.y + v.z * a.z + v.w * a.w;
    float sr = v.x * b.x + v.y * b.y + v.z * b.z + v.w * b.w;
    #pragma unroll
    for (int o = 32; o; o >>= 1) { sl += __shfl_xor(sl, o); sr += __shfl_xor(sr, o); }
    if (lane == 0) { xl[wave] = sl; xr[wave] = sr; }
}

// Per node: p = pos·w_e ; a = xl - p ; b = xr + p ; global max/min of a,b
__global__ void k_ab(const float* __restrict__ xl, const float* __restrict__ xr,
                     const float* __restrict__ pos, const float* __restrict__ w_e,
                     float2* __restrict__ sA, float* __restrict__ B,
                     unsigned* sc, int n) {
    int i = blockIdx.x * blockDim.x + threadIdx.x;
    float amax, amin, bmax, bmin;
    if (i < n) {
        float p = pos[3 * i] * w_e[0] + pos[3 * i + 1] * w_e[1] + pos[3 * i + 2] * w_e[2];
        float xli = xl[i];
        float a = xli - p;
        float b = xr[i] + p;
        sA[i] = make_float2(a, xli);
        B[i] = b;
        amax = amin = a; bmax = bmin = b;
    } else {
        amax = bmax = -INFINITY; amin = bmin = INFINITY;
    }
    #pragma unroll
    for (int o = 32; o; o >>= 1) {
        amax = fmaxf(amax, __shfl_xor(amax, o));
        bmax = fmaxf(bmax, __shfl_xor(bmax, o));
        amin = fminf(amin, __shfl_xor(amin, o));
        bmin = fminf(bmin, __shfl_xor(bmin, o));
    }
    __shared__ float s4[4][4];
    int w = threadIdx.x >> 6, l = threadIdx.x & 63;
    if (l == 0) { s4[w][0] = amax; s4[w][1] = bmax; s4[w][2] = amin; s4[w][3] = bmin; }
    __syncthreads();
    if (threadIdx.x == 0) {
        float AM = s4[0][0], BM = s4[0][1], Am = s4[0][2], Bm = s4[0][3];
        #pragma unroll
        for (int k = 1; k < 4; ++k) {
            AM = fmaxf(AM, s4[k][0]); BM = fmaxf(BM, s4[k][1]);
            Am = fminf(Am, s4[k][2]); Bm = fminf(Bm, s4[k][3]);
        }
        atomicMax(&sc[4], fmap(AM)); atomicMax(&sc[5], fmap(BM));
        atomicMin(&sc[6], fmap(Am)); atomicMin(&sc[7], fmap(Bm));
    }
}

// M = upper bound of e = att*leaky(a+b) over all edges (shift for softmax stability)
__global__ void k_setM(unsigned* sc, const float* __restrict__ att) {
    float at = att[0];
    float z = (at >= 0.f) ? (funmap(sc[4]) + funmap(sc[5]))
                          : (funmap(sc[6]) + funmap(sc[7]));
    float lz = (z >= 0.f) ? z : NEG_SLOPE * z;
    ((float*)sc)[3] = lz * at;
}

// Single edge pass: ex = exp(e - M); accumulate (ssum, numer) per dst
__global__ void k_edge_sum(const int* __restrict__ src, const int* __restrict__ dst,
                           const float2* __restrict__ sA, const float* __restrict__ B,
                           const float* __restrict__ att, const unsigned* __restrict__ sc,
                           float2* NS, int E) {
    int i = blockIdx.x * blockDim.x + threadIdx.x;
    if (i >= E) return;
    int s = src[i], d = dst[i];
    float2 sa = sA[s];
    float msg = sa.x + B[d];
    float lr = (msg >= 0.f) ? msg : NEG_SLOPE * msg;
    float ex = expf(lr * att[0] - ((const float*)sc)[3]);
    atomicAdd(&NS[d].x, ex);
    atomicAdd(&NS[d].y, ex * sa.y);
}

__global__ void k_logits(const float2* __restrict__ NS, const float* __restrict__ bias,
                         float* __restrict__ logits, unsigned* sc, int n) {
    int i = blockIdx.x * blockDim.x + threadIdx.x;
    unsigned mu = 0u;
    if (i < n) {
        float2 ns = NS[i];
        float lg = ns.y / (ns.x + 1e-38f) + bias[0];
        logits[i] = lg;
        mu = fmap(lg);
    }
    #pragma unroll
    for (int o = 32; o; o >>= 1) { unsigned t = __shfl_xor(mu, o); mu = (t > mu) ? t : mu; }
    if ((threadIdx.x & 63) == 0) atomicMax(&sc[0], mu);
}

__global__ void k_sumarg(const float* __restrict__ logits, unsigned* sc, int n) {
    int i = blockIdx.x * blockDim.x + threadIdx.x;
    unsigned gmax_u = sc[0];
    float gmax = funmap(gmax_u);
    float ex = 0.f;
    if (i < n) {
        float lg = logits[i];
        ex = expf(lg - gmax);
        if (fmap(lg) == gmax_u) atomicMin(&sc[2], (unsigned)i);
    }
    #pragma unroll
    for (int o = 32; o; o >>= 1) ex += __shfl_xor(ex, o);
    if ((threadIdx.x & 63) == 0) atomicAdd((float*)&sc[1], ex);
}

__global__ void k_score(const float* __restrict__ logits, const unsigned* __restrict__ sc,
                        float* __restrict__ out, int* rA, int n) {
    int i = blockIdx.x * blockDim.x + threadIdx.x;
    if (i >= n) return;
    float gmax = funmap(sc[0]);
    float gsum = ((const float*)sc)[1];
    out[i] = expf(logits[i] - gmax) / gsum;
    if (i == (int)sc[2]) rA[i] = 1;
}

__global__ void k_copy4(const int4* __restrict__ cur, int4* __restrict__ nxt, int n4) {
    int i = blockIdx.x * blockDim.x + threadIdx.x;
    if (i < n4) nxt[i] = cur[i];
}

__global__ void k_bfs4(const int4* __restrict__ src4, const int4* __restrict__ dst4,
                       const int* __restrict__ cur, int* __restrict__ nxt, int E4) {
    int i = blockIdx.x * blockDim.x + threadIdx.x;
    if (i >= E4) return;
    int4 s = src4[i];
    int4 d = dst4[i];
    if (cur[s.x]) nxt[d.x] = 1;
    if (cur[s.y]) nxt[d.y] = 1;
    if (cur[s.z]) nxt[d.z] = 1;
    if (cur[s.w]) nxt[d.w] = 1;
}

// 256 threads = 256 columns; block-strided rows; coalesced x reads
__global__ void k_pool(const float* __restrict__ x, const int* __restrict__ reach,
                       unsigned* pooled_u, int n) {
    int t = threadIdx.x;
    float local = -INFINITY;
    for (int node = blockIdx.x; node < n; node += gridDim.x) {
        if (reach[node]) local = fmaxf(local, x[(size_t)node * D_FEAT + t]);
    }
    atomicMax(&pooled_u[t], fmap(local));
}

__global__ void k_poolwrite(const unsigned* __restrict__ pooled_u, float* __restrict__ out, int n) {
    int t = threadIdx.x;
    out[n + t] = funmap(pooled_u[t]);
}

extern "C" void kernel_launch(void* const* d_in, const int* in_sizes, int n_in,
                              void* d_out, int out_size, void* d_ws, size_t ws_size,
                              hipStream_t stream) {
    const float* x    = (const float*)d_in[0];
    const float* pos  = (const float*)d_in[1];
    const float* w_l  = (const float*)d_in[2];
    const float* w_r  = (const float*)d_in[3];
    const float* w_e  = (const float*)d_in[4];
    const float* att  = (const float*)d_in[5];
    const float* bias = (const float*)d_in[6];
    const int*   ei   = (const int*)d_in[7];

    const int n = in_sizes[0] / D_FEAT;     // 100000
    const int E = in_sizes[7] / 2;          // 3200000
    const int* src = ei;
    const int* dst = ei + E;

    float* f0 = (float*)d_ws;
    float*    xl       = f0;
    float*    xr       = f0 + (size_t)n;
    float2*   sA       = (float2*)(f0 + 2 * (size_t)n);
    float*    B        = f0 + 4 * (size_t)n;
    float2*   NS       = (float2*)(f0 + 5 * (size_t)n);
    float*    logits   = f0 + 7 * (size_t)n;
    int*      rA       = (int*)(f0 + 8 * (size_t)n);
    int*      rB       = (int*)(f0 + 9 * (size_t)n);
    unsigned* pooled_u = (unsigned*)(f0 + 10 * (size_t)n);
    unsigned* sc       = (unsigned*)(f0 + 10 * (size_t)n + D_FEAT);

    float* out = (float*)d_out;

    const int Bk = 256;
    const int gN  = (n + Bk - 1) / Bk;
    const int gE  = (E + Bk - 1) / Bk;
    const int gD  = (n + 3) / 4;           // 4 waves/block, 1 wave/node
    const int n4  = n / 4;                 // 100000 % 4 == 0
    const int E4  = E / 4;                 // 3200000 % 4 == 0
    const int gN4 = (n4 + Bk - 1) / Bk;
    const int gE4 = (E4 + Bk - 1) / Bk;

    k_init<<<gN, Bk, 0, stream>>>(NS, rA, rB, pooled_u, sc, n);
    k_dots<<<gD, Bk, 0, stream>>>(x, w_l, w_r, xl, xr, n);
    k_ab<<<gN, Bk, 0, stream>>>(xl, xr, pos, w_e, sA, B, sc, n);
    k_setM<<<1, 1, 0, stream>>>(sc, att);
    k_edge_sum<<<gE, Bk, 0, stream>>>(src, dst, sA, B, att, sc, NS, E);
    k_logits<<<gN, Bk, 0, stream>>>(NS, bias, logits, sc, n);
    k_sumarg<<<gN, Bk, 0, stream>>>(logits, sc, n);
    k_score<<<gN, Bk, 0, stream>>>(logits, sc, out, rA, n);

    int* cur = rA;
    int* nxt = rB;
    for (int it = 0; it < 5; ++it) {
        k_copy4<<<gN4, Bk, 0, stream>>>((const int4*)cur, (int4*)nxt, n4);
        k_bfs4<<<gE4, Bk, 0, stream>>>((const int4*)src, (const int4*)dst, cur, nxt, E4);
        int* t = cur; cur = nxt; nxt = t;
    }

    k_pool<<<2048, Bk, 0, stream>>>(x, cur, pooled_u, n);
    k_poolwrite<<<1, Bk, 0, stream>>>(pooled_u, out, n);
}

// Round 3
// 382.418 us; speedup vs baseline: 1.7893x; 1.5032x over previous
//
#include <hip/hip_runtime.h>

#define D_FEAT 256
#define NEG_SLOPE 0.2f
#define MAXBINS 512

// Monotone float -> uint map (order-preserving, includes +-inf)
__device__ __forceinline__ unsigned fmap(float f) {
    unsigned u = __float_as_uint(f);
    return (u & 0x80000000u) ? ~u : (u | 0x80000000u);
}
__device__ __forceinline__ float funmap(unsigned u) {
    return __uint_as_float((u & 0x80000000u) ? (u ^ 0x80000000u) : ~u);
}

// sc layout: [0] gmax_u  [1] gsum(f32)  [2] argmin  [3] M(f32)
//            [4] maxA_u  [5] maxB_u     [6] minA_u  [7] minB_u

__global__ void k_init(float2* NS, int* rA, int* rB, unsigned* pooled_u, unsigned* sc,
                       unsigned* gHist, int n) {
    int i = blockIdx.x * blockDim.x + threadIdx.x;
    if (i < n) { NS[i] = make_float2(0.f, 0.f); rA[i] = 0; rB[i] = 0; }
    if (i < D_FEAT) pooled_u[i] = 0u;
    if (i < MAXBINS) gHist[i] = 0u;
    if (i == 0) {
        sc[0] = 0u; ((float*)sc)[1] = 0.f; sc[2] = 0xFFFFFFFFu;
        sc[4] = 0u; sc[5] = 0u; sc[6] = 0xFFFFFFFFu; sc[7] = 0xFFFFFFFFu;
    }
}

// One wave per node: xl[i] = x[i,:]·w_l, xr[i] = x[i,:]·w_r
__global__ void k_dots(const float* __restrict__ x, const float* __restrict__ w_l,
                       const float* __restrict__ w_r, float* __restrict__ xl,
                       float* __restrict__ xr, int n) {
    int wave = (int)((blockIdx.x * blockDim.x + threadIdx.x) >> 6);
    int lane = threadIdx.x & 63;
    if (wave >= n) return;
    const float4* xv = (const float4*)(x + (size_t)wave * D_FEAT);
    float4 v = xv[lane];
    float4 a = ((const float4*)w_l)[lane];
    float4 b = ((const float4*)w_r)[lane];
    float sl = v.x * a.x + v.y * a.y + v.z * a.z + v.w * a.w;
    float sr = v.x * b.x + v.y * b.y + v.z * b.z + v.w * b.w;
    #pragma unroll
    for (int o = 32; o; o >>= 1) { sl += __shfl_xor(sl, o); sr += __shfl_xor(sr, o); }
    if (lane == 0) { xl[wave] = sl; xr[wave] = sr; }
}

// Per node: p = pos·w_e ; a = xl - p ; b = xr + p ; global max/min of a,b
__global__ void k_ab(const float* __restrict__ xl, const float* __restrict__ xr,
                     const float* __restrict__ pos, const float* __restrict__ w_e,
                     float2* __restrict__ sA, float* __restrict__ B,
                     unsigned* sc, int n) {
    int i = blockIdx.x * blockDim.x + threadIdx.x;
    float amax, amin, bmax, bmin;
    if (i < n) {
        float p = pos[3 * i] * w_e[0] + pos[3 * i + 1] * w_e[1] + pos[3 * i + 2] * w_e[2];
        float xli = xl[i];
        float a = xli - p;
        float b = xr[i] + p;
        sA[i] = make_float2(a, xli);
        B[i] = b;
        amax = amin = a; bmax = bmin = b;
    } else {
        amax = bmax = -INFINITY; amin = bmin = INFINITY;
    }
    #pragma unroll
    for (int o = 32; o; o >>= 1) {
        amax = fmaxf(amax, __shfl_xor(amax, o));
        bmax = fmaxf(bmax, __shfl_xor(bmax, o));
        amin = fminf(amin, __shfl_xor(amin, o));
        bmin = fminf(bmin, __shfl_xor(bmin, o));
    }
    __shared__ float s4[4][4];
    int w = threadIdx.x >> 6, l = threadIdx.x & 63;
    if (l == 0) { s4[w][0] = amax; s4[w][1] = bmax; s4[w][2] = amin; s4[w][3] = bmin; }
    __syncthreads();
    if (threadIdx.x == 0) {
        float AM = s4[0][0], BM = s4[0][1], Am = s4[0][2], Bm = s4[0][3];
        #pragma unroll
        for (int k = 1; k < 4; ++k) {
            AM = fmaxf(AM, s4[k][0]); BM = fmaxf(BM, s4[k][1]);
            Am = fminf(Am, s4[k][2]); Bm = fminf(Bm, s4[k][3]);
        }
        atomicMax(&sc[4], fmap(AM)); atomicMax(&sc[5], fmap(BM));
        atomicMin(&sc[6], fmap(Am)); atomicMin(&sc[7], fmap(Bm));
    }
}

// M = upper bound of e over all edges (global shift for softmax stability)
__global__ void k_setM(unsigned* sc, const float* __restrict__ att) {
    float at = att[0];
    float z = (at >= 0.f) ? (funmap(sc[4]) + funmap(sc[5]))
                          : (funmap(sc[6]) + funmap(sc[7]));
    float lz = (z >= 0.f) ? z : NEG_SLOPE * z;
    ((float*)sc)[3] = lz * at;
}

// ---------------- sorted (bin-scatter) path ----------------

__global__ void k_hist(const int4* __restrict__ dst4, int E4, int nbins,
                       unsigned* __restrict__ gHist) {
    __shared__ unsigned h[MAXBINS];
    for (int b = threadIdx.x; b < nbins; b += blockDim.x) h[b] = 0u;
    __syncthreads();
    int stride = gridDim.x * blockDim.x;
    for (int i = blockIdx.x * blockDim.x + threadIdx.x; i < E4; i += stride) {
        int4 d = dst4[i];
        atomicAdd(&h[d.x >> 8], 1u);
        atomicAdd(&h[d.y >> 8], 1u);
        atomicAdd(&h[d.z >> 8], 1u);
        atomicAdd(&h[d.w >> 8], 1u);
    }
    __syncthreads();
    for (int b = threadIdx.x; b < nbins; b += blockDim.x)
        if (h[b]) atomicAdd(&gHist[b], h[b]);
}

__global__ void k_scan(const unsigned* __restrict__ gHist, unsigned* __restrict__ gBase,
                       unsigned* __restrict__ gCursor, int nbins) {
    if (threadIdx.x == 0) {
        unsigned acc = 0;
        for (int b = 0; b < nbins; ++b) {
            gBase[b] = acc; gCursor[b] = acc; acc += gHist[b];
        }
        gBase[nbins] = acc;
    }
}

// 4096 edges/block, 16/thread. Computes ex, ex*xl and scatters 16B records bin-contiguously.
__global__ void k_scatter(const int* __restrict__ src, const int* __restrict__ dst,
                          const float2* __restrict__ sA, const float* __restrict__ B,
                          const float* __restrict__ att, const unsigned* __restrict__ sc,
                          unsigned* __restrict__ gCursor, int4* __restrict__ recs,
                          int E, int nbins) {
    __shared__ unsigned h[MAXBINS];
    __shared__ unsigned base[MAXBINS];
    for (int b = threadIdx.x; b < nbins; b += 256) h[b] = 0u;
    __syncthreads();
    const float at = att[0];
    const float M = ((const float*)sc)[3];
    int e0 = blockIdx.x * 4096 + threadIdx.x * 16;
    int   dl[16];
    float ex[16];
    float exl[16];
    #pragma unroll
    for (int k = 0; k < 16; ++k) dl[k] = -1;
    #pragma unroll
    for (int g = 0; g < 4; ++g) {
        int gi = e0 + g * 4;
        if (gi + 3 < E) {
            int4 sv = *(const int4*)(src + gi);
            int4 dv = *(const int4*)(dst + gi);
            int ss[4] = { sv.x, sv.y, sv.z, sv.w };
            int dd[4] = { dv.x, dv.y, dv.z, dv.w };
            #pragma unroll
            for (int j = 0; j < 4; ++j) {
                int s_ = ss[j], d_ = dd[j];
                float2 sa = sA[s_];
                float msg = sa.x + B[d_];
                float lr = (msg >= 0.f) ? msg : NEG_SLOPE * msg;
                float e = expf(lr * at - M);
                int k = g * 4 + j;
                dl[k] = d_; ex[k] = e; exl[k] = e * sa.y;
                atomicAdd(&h[d_ >> 8], 1u);
            }
        }
    }
    __syncthreads();
    for (int b = threadIdx.x; b < nbins; b += 256) {
        unsigned c = h[b];
        h[b] = 0u;
        base[b] = c ? atomicAdd(&gCursor[b], c) : 0u;
    }
    __syncthreads();
    #pragma unroll
    for (int k = 0; k < 16; ++k) {
        if (dl[k] >= 0) {
            int bin = dl[k] >> 8;
            unsigned off = atomicAdd(&h[bin], 1u);
            int4 r;
            r.x = dl[k];
            r.y = __float_as_int(ex[k]);
            r.z = __float_as_int(exl[k]);
            r.w = 0;
            recs[base[bin] + off] = r;
        }
    }
}

// One block per bin: LDS-only accumulation, fused logits + global max
__global__ void k_binsum(const int4* __restrict__ recs, const unsigned* __restrict__ gBase,
                         const float* __restrict__ bias, float* __restrict__ logits,
                         unsigned* sc, int n) {
    __shared__ float accx[256];
    __shared__ float accy[256];
    int b = blockIdx.x;
    int tid = threadIdx.x;
    accx[tid] = 0.f; accy[tid] = 0.f;
    __syncthreads();
    unsigned s0 = gBase[b], s1 = gBase[b + 1];
    for (unsigned i = s0 + tid; i < s1; i += 256u) {
        int4 r = recs[i];
        int loc = r.x & 255;
        atomicAdd(&accx[loc], __int_as_float(r.y));
        atomicAdd(&accy[loc], __int_as_float(r.z));
    }
    __syncthreads();
    int node = (b << 8) + tid;
    float lg = -INFINITY;
    if (node < n) {
        lg = accy[tid] / (accx[tid] + 1e-38f) + bias[0];
        logits[node] = lg;
    }
    unsigned mu = fmap(lg);
    #pragma unroll
    for (int o = 32; o; o >>= 1) { unsigned t = __shfl_xor(mu, o); mu = (t > mu) ? t : mu; }
    __shared__ unsigned wm[4];
    int w = tid >> 6, l = tid & 63;
    if (l == 0) wm[w] = mu;
    __syncthreads();
    if (tid == 0) {
        unsigned m = wm[0];
        #pragma unroll
        for (int k = 1; k < 4; ++k) m = (wm[k] > m) ? wm[k] : m;
        atomicMax(&sc[0], m);
    }
}

// ---------------- fallback (atomic) path ----------------

__global__ void k_edge_sum(const int* __restrict__ src, const int* __restrict__ dst,
                           const float2* __restrict__ sA, const float* __restrict__ B,
                           const float* __restrict__ att, const unsigned* __restrict__ sc,
                           float2* NS, int E) {
    int i = blockIdx.x * blockDim.x + threadIdx.x;
    if (i >= E) return;
    int s = src[i], d = dst[i];
    float2 sa = sA[s];
    float msg = sa.x + B[d];
    float lr = (msg >= 0.f) ? msg : NEG_SLOPE * msg;
    float ex = expf(lr * att[0] - ((const float*)sc)[3]);
    atomicAdd(&NS[d].x, ex);
    atomicAdd(&NS[d].y, ex * sa.y);
}

__global__ void k_logits(const float2* __restrict__ NS, const float* __restrict__ bias,
                         float* __restrict__ logits, unsigned* sc, int n) {
    int i = blockIdx.x * blockDim.x + threadIdx.x;
    unsigned mu = 0u;
    if (i < n) {
        float2 ns = NS[i];
        float lg = ns.y / (ns.x + 1e-38f) + bias[0];
        logits[i] = lg;
        mu = fmap(lg);
    }
    #pragma unroll
    for (int o = 32; o; o >>= 1) { unsigned t = __shfl_xor(mu, o); mu = (t > mu) ? t : mu; }
    if ((threadIdx.x & 63) == 0) atomicMax(&sc[0], mu);
}

// ---------------- tail: global softmax, argmax, BFS, pool ----------------

__global__ void k_sumarg(const float* __restrict__ logits, unsigned* sc, int n) {
    int i = blockIdx.x * blockDim.x + threadIdx.x;
    unsigned gmax_u = sc[0];
    float gmax = funmap(gmax_u);
    float ex = 0.f;
    if (i < n) {
        float lg = logits[i];
        ex = expf(lg - gmax);
        if (fmap(lg) == gmax_u) atomicMin(&sc[2], (unsigned)i);
    }
    #pragma unroll
    for (int o = 32; o; o >>= 1) ex += __shfl_xor(ex, o);
    if ((threadIdx.x & 63) == 0) atomicAdd((float*)&sc[1], ex);
}

__global__ void k_score(const float* __restrict__ logits, const unsigned* __restrict__ sc,
                        float* __restrict__ out, int* rA, int n) {
    int i = blockIdx.x * blockDim.x + threadIdx.x;
    if (i >= n) return;
    float gmax = funmap(sc[0]);
    float gsum = ((const float*)sc)[1];
    out[i] = expf(logits[i] - gmax) / gsum;
    if (i == (int)sc[2]) rA[i] = 1;
}

__global__ void k_copy4(const int4* __restrict__ cur, int4* __restrict__ nxt, int n4) {
    int i = blockIdx.x * blockDim.x + threadIdx.x;
    if (i < n4) nxt[i] = cur[i];
}

__global__ void k_bfs4(const int4* __restrict__ src4, const int4* __restrict__ dst4,
                       const int* __restrict__ cur, int* __restrict__ nxt, int E4) {
    int i = blockIdx.x * blockDim.x + threadIdx.x;
    if (i >= E4) return;
    int4 s = src4[i];
    int4 d = dst4[i];
    if (cur[s.x]) nxt[d.x] = 1;
    if (cur[s.y]) nxt[d.y] = 1;
    if (cur[s.z]) nxt[d.z] = 1;
    if (cur[s.w]) nxt[d.w] = 1;
}

__global__ void k_pool(const float* __restrict__ x, const int* __restrict__ reach,
                       unsigned* pooled_u, int n) {
    int t = threadIdx.x;
    float local = -INFINITY;
    for (int node = blockIdx.x; node < n; node += gridDim.x) {
        if (reach[node]) local = fmaxf(local, x[(size_t)node * D_FEAT + t]);
    }
    atomicMax(&pooled_u[t], fmap(local));
}

__global__ void k_poolwrite(const unsigned* __restrict__ pooled_u, float* __restrict__ out, int n) {
    int t = threadIdx.x;
    out[n + t] = funmap(pooled_u[t]);
}

extern "C" void kernel_launch(void* const* d_in, const int* in_sizes, int n_in,
                              void* d_out, int out_size, void* d_ws, size_t ws_size,
                              hipStream_t stream) {
    const float* x    = (const float*)d_in[0];
    const float* pos  = (const float*)d_in[1];
    const float* w_l  = (const float*)d_in[2];
    const float* w_r  = (const float*)d_in[3];
    const float* w_e  = (const float*)d_in[4];
    const float* att  = (const float*)d_in[5];
    const float* bias = (const float*)d_in[6];
    const int*   ei   = (const int*)d_in[7];

    const int n = in_sizes[0] / D_FEAT;     // 100000
    const int E = in_sizes[7] / 2;          // 3200000
    const int* src = ei;
    const int* dst = ei + E;
    const int nbins = (n + 255) >> 8;       // 391

    float* f0 = (float*)d_ws;
    float*    xl       = f0;
    float*    xr       = f0 + (size_t)n;
    float2*   sA       = (float2*)(f0 + 2 * (size_t)n);
    float*    B        = f0 + 4 * (size_t)n;
    float*    logits   = f0 + 5 * (size_t)n;
    int*      rA       = (int*)(f0 + 6 * (size_t)n);
    int*      rB       = (int*)(f0 + 7 * (size_t)n);
    float2*   NS       = (float2*)(f0 + 8 * (size_t)n);     // fallback only
    unsigned* pooled_u = (unsigned*)(f0 + 10 * (size_t)n);
    unsigned* sc       = (unsigned*)(f0 + 10 * (size_t)n + 256);
    unsigned* gHist    = (unsigned*)(f0 + 10 * (size_t)n + 320);
    unsigned* gBase    = (unsigned*)(f0 + 10 * (size_t)n + 832);
    unsigned* gCursor  = (unsigned*)(f0 + 10 * (size_t)n + 1345 + 3); // 4-aligned
    size_t recsOff = ((10 * (size_t)n + 1860) + 3) & ~(size_t)3;      // float index, 16B-aligned
    int4*     recs     = (int4*)(f0 + recsOff);

    size_t need_bytes = (recsOff + 4 * (size_t)E) * sizeof(float);
    const bool sorted_ok = (ws_size >= need_bytes) && (nbins <= MAXBINS) && (E % 4 == 0);

    float* out = (float*)d_out;

    const int Bk = 256;
    const int gN  = (n + Bk - 1) / Bk;
    const int gE  = (E + Bk - 1) / Bk;
    const int gD  = (n + 3) / 4;           // k_dots: 4 waves/block, 1 wave/node
    const int n4  = n / 4;
    const int E4  = E / 4;
    const int gN4 = (n4 + Bk - 1) / Bk;
    const int gE4 = (E4 + Bk - 1) / Bk;

    k_init<<<gN, Bk, 0, stream>>>(NS, rA, rB, pooled_u, sc, gHist, n);
    k_dots<<<gD, Bk, 0, stream>>>(x, w_l, w_r, xl, xr, n);
    k_ab<<<gN, Bk, 0, stream>>>(xl, xr, pos, w_e, sA, B, sc, n);
    k_setM<<<1, 64, 0, stream>>>(sc, att);

    if (sorted_ok) {
        k_hist<<<512, Bk, 0, stream>>>((const int4*)dst, E4, nbins, gHist);
        k_scan<<<1, 64, 0, stream>>>(gHist, gBase, gCursor, nbins);
        k_scatter<<<(E + 4095) / 4096, Bk, 0, stream>>>(src, dst, sA, B, att, sc,
                                                        gCursor, recs, E, nbins);
        k_binsum<<<nbins, Bk, 0, stream>>>(recs, gBase, bias, logits, sc, n);
    } else {
        k_edge_sum<<<gE, Bk, 0, stream>>>(src, dst, sA, B, att, sc, NS, E);
        k_logits<<<gN, Bk, 0, stream>>>(NS, bias, logits, sc, n);
    }

    k_sumarg<<<gN, Bk, 0, stream>>>(logits, sc, n);
    k_score<<<gN, Bk, 0, stream>>>(logits, sc, out, rA, n);

    int* cur = rA;
    int* nxt = rB;
    for (int it = 0; it < 5; ++it) {
        k_copy4<<<gN4, Bk, 0, stream>>>((const int4*)cur, (int4*)nxt, n4);
        k_bfs4<<<gE4, Bk, 0, stream>>>((const int4*)src, (const int4*)dst, cur, nxt, E4);
        int* t = cur; cur = nxt; nxt = t;
    }

    k_pool<<<2048, Bk, 0, stream>>>(x, cur, pooled_u, n);
    k_poolwrite<<<1, Bk, 0, stream>>>(pooled_u, out, n);
}

// Round 4
// 372.764 us; speedup vs baseline: 1.8357x; 1.0259x over previous
//
#include <hip/hip_runtime.h>

#define D_FEAT 256
#define NEG_SLOPE 0.2f
#define MAXBINS 512

// Monotone float -> uint map (order-preserving, includes +-inf)
__device__ __forceinline__ unsigned fmap(float f) {
    unsigned u = __float_as_uint(f);
    return (u & 0x80000000u) ? ~u : (u | 0x80000000u);
}
__device__ __forceinline__ float funmap(unsigned u) {
    return __uint_as_float((u & 0x80000000u) ? (u ^ 0x80000000u) : ~u);
}

// sc layout: [0] gmax_u  [1] gsum(f32)  [2] argmin  [3] M(f32)
//            [4] maxA_u  [5] maxB_u     [6] minA_u  [7] minB_u

__global__ void k_init(float2* NS, unsigned* stampW, int nW, unsigned* pooled_u,
                       unsigned* sc, unsigned* gHist, int n) {
    int i = blockIdx.x * blockDim.x + threadIdx.x;
    if (i < n) NS[i] = make_float2(0.f, 0.f);
    if (i < nW) stampW[i] = 0xFFFFFFFFu;       // stamp bytes = 0xFF (unreached)
    if (i < D_FEAT) pooled_u[i] = 0u;
    if (i < MAXBINS) gHist[i] = 0u;
    if (i == 0) {
        sc[0] = 0u; ((float*)sc)[1] = 0.f; sc[2] = 0xFFFFFFFFu;
        sc[4] = 0u; sc[5] = 0u; sc[6] = 0xFFFFFFFFu; sc[7] = 0xFFFFFFFFu;
    }
}

// One wave per node: xl[i] = x[i,:]·w_l, xr[i] = x[i,:]·w_r
__global__ void k_dots(const float* __restrict__ x, const float* __restrict__ w_l,
                       const float* __restrict__ w_r, float* __restrict__ xl,
                       float* __restrict__ xr, int n) {
    int wave = (int)((blockIdx.x * blockDim.x + threadIdx.x) >> 6);
    int lane = threadIdx.x & 63;
    if (wave >= n) return;
    const float4* xv = (const float4*)(x + (size_t)wave * D_FEAT);
    float4 v = xv[lane];
    float4 a = ((const float4*)w_l)[lane];
    float4 b = ((const float4*)w_r)[lane];
    float sl = v.x * a.x + v.y * a.y + v.z * a.z + v.w * a.w;
    float sr = v.x * b.x + v.y * b.y + v.z * b.z + v.w * b.w;
    #pragma unroll
    for (int o = 32; o; o >>= 1) { sl += __shfl_xor(sl, o); sr += __shfl_xor(sr, o); }
    if (lane == 0) { xl[wave] = sl; xr[wave] = sr; }
}

// Per node: p = pos·w_e ; a = xl - p ; b = xr + p ; global max/min of a,b
__global__ void k_ab(const float* __restrict__ xl, const float* __restrict__ xr,
                     const float* __restrict__ pos, const float* __restrict__ w_e,
                     float2* __restrict__ sA, float* __restrict__ B,
                     unsigned* sc, int n) {
    int i = blockIdx.x * blockDim.x + threadIdx.x;
    float amax, amin, bmax, bmin;
    if (i < n) {
        float p = pos[3 * i] * w_e[0] + pos[3 * i + 1] * w_e[1] + pos[3 * i + 2] * w_e[2];
        float xli = xl[i];
        float a = xli - p;
        float b = xr[i] + p;
        sA[i] = make_float2(a, xli);
        B[i] = b;
        amax = amin = a; bmax = bmin = b;
    } else {
        amax = bmax = -INFINITY; amin = bmin = INFINITY;
    }
    #pragma unroll
    for (int o = 32; o; o >>= 1) {
        amax = fmaxf(amax, __shfl_xor(amax, o));
        bmax = fmaxf(bmax, __shfl_xor(bmax, o));
        amin = fminf(amin, __shfl_xor(amin, o));
        bmin = fminf(bmin, __shfl_xor(bmin, o));
    }
    __shared__ float s4[4][4];
    int w = threadIdx.x >> 6, l = threadIdx.x & 63;
    if (l == 0) { s4[w][0] = amax; s4[w][1] = bmax; s4[w][2] = amin; s4[w][3] = bmin; }
    __syncthreads();
    if (threadIdx.x == 0) {
        float AM = s4[0][0], BM = s4[0][1], Am = s4[0][2], Bm = s4[0][3];
        #pragma unroll
        for (int k = 1; k < 4; ++k) {
            AM = fmaxf(AM, s4[k][0]); BM = fmaxf(BM, s4[k][1]);
            Am = fminf(Am, s4[k][2]); Bm = fminf(Bm, s4[k][3]);
        }
        atomicMax(&sc[4], fmap(AM)); atomicMax(&sc[5], fmap(BM));
        atomicMin(&sc[6], fmap(Am)); atomicMin(&sc[7], fmap(Bm));
    }
}

// ---------------- sorted (bin-scatter) path ----------------

__global__ void k_hist(const int4* __restrict__ dst4, int E4, int nbins,
                       unsigned* __restrict__ gHist) {
    __shared__ unsigned h[MAXBINS];
    for (int b = threadIdx.x; b < nbins; b += blockDim.x) h[b] = 0u;
    __syncthreads();
    int stride = gridDim.x * blockDim.x;
    for (int i = blockIdx.x * blockDim.x + threadIdx.x; i < E4; i += stride) {
        int4 d = dst4[i];
        atomicAdd(&h[d.x >> 8], 1u);
        atomicAdd(&h[d.y >> 8], 1u);
        atomicAdd(&h[d.z >> 8], 1u);
        atomicAdd(&h[d.w >> 8], 1u);
    }
    __syncthreads();
    for (int b = threadIdx.x; b < nbins; b += blockDim.x)
        if (h[b]) atomicAdd(&gHist[b], h[b]);
}

// One block, 64 lanes: wave-parallel exclusive scan of gHist + compute M (ex-setM)
__global__ void k_scan(const unsigned* __restrict__ gHist, unsigned* __restrict__ gBase,
                       unsigned* __restrict__ gCursor, int nbins,
                       unsigned* sc, const float* __restrict__ att) {
    int lane = threadIdx.x;
    if (lane == 0) {
        float at = att[0];
        float z = (at >= 0.f) ? (funmap(sc[4]) + funmap(sc[5]))
                              : (funmap(sc[6]) + funmap(sc[7]));
        float lz = (z >= 0.f) ? z : NEG_SLOPE * z;
        ((float*)sc)[3] = lz * at;
    }
    unsigned carry = 0;
    for (int b0 = 0; b0 < nbins; b0 += 64) {
        int b = b0 + lane;
        unsigned v = (b < nbins) ? gHist[b] : 0u;
        unsigned inc = v;
        #pragma unroll
        for (int o = 1; o < 64; o <<= 1) {
            unsigned t = __shfl_up(inc, o);
            if (lane >= o) inc += t;
        }
        unsigned excl = inc - v + carry;
        if (b < nbins) { gBase[b] = excl; gCursor[b] = excl; }
        carry += __shfl(inc, 63);
    }
    if (lane == 0) gBase[nbins] = carry;
}

// 4096 edges/block. Loop1: LDS hist of dst bins. Reserve global bases.
// Loop2: re-read edges (L2-hot), recompute ex once, scatter 16B records.
__global__ void k_scatter(const int4* __restrict__ src4, const int4* __restrict__ dst4,
                          const float2* __restrict__ sA, const float* __restrict__ B,
                          const float* __restrict__ att, const unsigned* __restrict__ sc,
                          unsigned* __restrict__ gCursor, int4* __restrict__ recs,
                          int E4, int nbins) {
    __shared__ unsigned h[MAXBINS];
    __shared__ unsigned base[MAXBINS];
    for (int b = threadIdx.x; b < nbins; b += 256) h[b] = 0u;
    __syncthreads();
    int b4 = blockIdx.x * 1024;   // int4 index base (4096 edges)
    #pragma unroll
    for (int g = 0; g < 4; ++g) {
        int idx = b4 + g * 256 + threadIdx.x;
        if (idx < E4) {
            int4 d = dst4[idx];
            atomicAdd(&h[d.x >> 8], 1u);
            atomicAdd(&h[d.y >> 8], 1u);
            atomicAdd(&h[d.z >> 8], 1u);
            atomicAdd(&h[d.w >> 8], 1u);
        }
    }
    __syncthreads();
    for (int b = threadIdx.x; b < nbins; b += 256) {
        unsigned c = h[b];
        h[b] = 0u;
        base[b] = c ? atomicAdd(&gCursor[b], c) : 0u;
    }
    __syncthreads();
    const float at = att[0];
    const float M = ((const float*)sc)[3];
    #pragma unroll
    for (int g = 0; g < 4; ++g) {
        int idx = b4 + g * 256 + threadIdx.x;
        if (idx < E4) {
            int4 sv = src4[idx];
            int4 dv = dst4[idx];
            int ss[4] = { sv.x, sv.y, sv.z, sv.w };
            int dd[4] = { dv.x, dv.y, dv.z, dv.w };
            #pragma unroll
            for (int j = 0; j < 4; ++j) {
                int s_ = ss[j], d_ = dd[j];
                float2 sa = sA[s_];
                float msg = sa.x + B[d_];
                float lr = (msg >= 0.f) ? msg : NEG_SLOPE * msg;
                float e = expf(lr * at - M);
                int bin = d_ >> 8;
                unsigned off = atomicAdd(&h[bin], 1u);
                int4 r;
                r.x = d_;
                r.y = __float_as_int(e);
                r.z = __float_as_int(e * sa.y);
                r.w = 0;
                recs[base[bin] + off] = r;
            }
        }
    }
}

// One block per bin: LDS-only accumulation, fused logits + global max
__global__ void k_binsum(const int4* __restrict__ recs, const unsigned* __restrict__ gBase,
                         const float* __restrict__ bias, float* __restrict__ logits,
                         unsigned* sc, int n) {
    __shared__ float accx[256];
    __shared__ float accy[256];
    int b = blockIdx.x;
    int tid = threadIdx.x;
    accx[tid] = 0.f; accy[tid] = 0.f;
    __syncthreads();
    unsigned s0 = gBase[b], s1 = gBase[b + 1];
    for (unsigned i = s0 + tid; i < s1; i += 256u) {
        int4 r = recs[i];
        int loc = r.x & 255;
        atomicAdd(&accx[loc], __int_as_float(r.y));
        atomicAdd(&accy[loc], __int_as_float(r.z));
    }
    __syncthreads();
    int node = (b << 8) + tid;
    float lg = -INFINITY;
    if (node < n) {
        lg = accy[tid] / (accx[tid] + 1e-38f) + bias[0];
        logits[node] = lg;
    }
    unsigned mu = fmap(lg);
    #pragma unroll
    for (int o = 32; o; o >>= 1) { unsigned t = __shfl_xor(mu, o); mu = (t > mu) ? t : mu; }
    __shared__ unsigned wm[4];
    int w = tid >> 6, l = tid & 63;
    if (l == 0) wm[w] = mu;
    __syncthreads();
    if (tid == 0) {
        unsigned m = wm[0];
        #pragma unroll
        for (int k = 1; k < 4; ++k) m = (wm[k] > m) ? wm[k] : m;
        atomicMax(&sc[0], m);
    }
}

// ---------------- fallback (atomic) path ----------------

__global__ void k_edge_sum(const int* __restrict__ src, const int* __restrict__ dst,
                           const float2* __restrict__ sA, const float* __restrict__ B,
                           const float* __restrict__ att, const unsigned* __restrict__ sc,
                           float2* NS, int E) {
    int i = blockIdx.x * blockDim.x + threadIdx.x;
    if (i >= E) return;
    int s = src[i], d = dst[i];
    float2 sa = sA[s];
    float msg = sa.x + B[d];
    float lr = (msg >= 0.f) ? msg : NEG_SLOPE * msg;
    float ex = expf(lr * att[0] - ((const float*)sc)[3]);
    atomicAdd(&NS[d].x, ex);
    atomicAdd(&NS[d].y, ex * sa.y);
}

__global__ void k_logits(const float2* __restrict__ NS, const float* __restrict__ bias,
                         float* __restrict__ logits, unsigned* sc, int n) {
    int i = blockIdx.x * blockDim.x + threadIdx.x;
    unsigned mu = 0u;
    if (i < n) {
        float2 ns = NS[i];
        float lg = ns.y / (ns.x + 1e-38f) + bias[0];
        logits[i] = lg;
        mu = fmap(lg);
    }
    #pragma unroll
    for (int o = 32; o; o >>= 1) { unsigned t = __shfl_xor(mu, o); mu = (t > mu) ? t : mu; }
    if ((threadIdx.x & 63) == 0) atomicMax(&sc[0], mu);
}

// ---------------- tail: global softmax, argmax, BFS, pool ----------------

__global__ void k_sumarg(const float* __restrict__ logits, unsigned* sc, int n) {
    int i = blockIdx.x * blockDim.x + threadIdx.x;
    unsigned gmax_u = sc[0];
    float gmax = funmap(gmax_u);
    float ex = 0.f;
    if (i < n) {
        float lg = logits[i];
        ex = expf(lg - gmax);
        if (fmap(lg) == gmax_u) atomicMin(&sc[2], (unsigned)i);
    }
    #pragma unroll
    for (int o = 32; o; o >>= 1) ex += __shfl_xor(ex, o);
    if ((threadIdx.x & 63) == 0) atomicAdd((float*)&sc[1], ex);
}

// score + seed the BFS stamp at argmax
__global__ void k_score(const float* __restrict__ logits, const unsigned* __restrict__ sc,
                        float* __restrict__ out, unsigned char* stamp, int n) {
    int i = blockIdx.x * blockDim.x + threadIdx.x;
    if (i >= n) return;
    float gmax = funmap(sc[0]);
    float gsum = ((const float*)sc)[1];
    out[i] = expf(logits[i] - gmax) / gsum;
    if (i == (int)sc[2]) stamp[i] = 0;
}

// In-place timestamp BFS pass t: stamp[dst] = t if stamp[src] reached before t.
// All same-pass writes store exactly t -> races are idempotent; no copy needed.
__global__ void k_bfs_stamp(const int4* __restrict__ src4, const int4* __restrict__ dst4,
                            unsigned char* __restrict__ stamp, int E4, int t) {
    int i = blockIdx.x * blockDim.x + threadIdx.x;
    if (i >= E4) return;
    int4 s = src4[i];
    int4 d = dst4[i];
    unsigned char th = (unsigned char)t;
    if (stamp[s.x] < th && stamp[d.x] > th) stamp[d.x] = th;
    if (stamp[s.y] < th && stamp[d.y] > th) stamp[d.y] = th;
    if (stamp[s.z] < th && stamp[d.z] > th) stamp[d.z] = th;
    if (stamp[s.w] < th && stamp[d.w] > th) stamp[d.w] = th;
}

// 256 threads = 256 columns; block-strided rows; coalesced x reads
__global__ void k_pool(const float* __restrict__ x, const unsigned char* __restrict__ stamp,
                       unsigned* pooled_u, int n) {
    int t = threadIdx.x;
    float local = -INFINITY;
    for (int node = blockIdx.x; node < n; node += gridDim.x) {
        if (stamp[node] != 0xFF) local = fmaxf(local, x[(size_t)node * D_FEAT + t]);
    }
    atomicMax(&pooled_u[t], fmap(local));
}

__global__ void k_poolwrite(const unsigned* __restrict__ pooled_u, float* __restrict__ out, int n) {
    int t = threadIdx.x;
    out[n + t] = funmap(pooled_u[t]);
}

extern "C" void kernel_launch(void* const* d_in, const int* in_sizes, int n_in,
                              void* d_out, int out_size, void* d_ws, size_t ws_size,
                              hipStream_t stream) {
    const float* x    = (const float*)d_in[0];
    const float* pos  = (const float*)d_in[1];
    const float* w_l  = (const float*)d_in[2];
    const float* w_r  = (const float*)d_in[3];
    const float* w_e  = (const float*)d_in[4];
    const float* att  = (const float*)d_in[5];
    const float* bias = (const float*)d_in[6];
    const int*   ei   = (const int*)d_in[7];

    const int n = in_sizes[0] / D_FEAT;     // 100000
    const int E = in_sizes[7] / 2;          // 3200000
    const int* src = ei;
    const int* dst = ei + E;
    const int nbins = (n + 255) >> 8;       // 391
    const int nW = (n + 3) / 4;             // stamp words

    float* f0 = (float*)d_ws;
    size_t o = 0;
    float*    xl       = f0 + o; o += (size_t)n;
    float*    xr       = f0 + o; o += (size_t)n;
    float2*   sA       = (float2*)(f0 + o); o += 2 * (size_t)n;
    float*    B        = f0 + o; o += (size_t)n;
    float*    logits   = f0 + o; o += (size_t)n;
    float2*   NS       = (float2*)(f0 + o); o += 2 * (size_t)n;   // fallback only
    unsigned* stampW   = (unsigned*)(f0 + o); o += (size_t)nW;
    unsigned char* stamp = (unsigned char*)stampW;
    unsigned* pooled_u = (unsigned*)(f0 + o); o += 256;
    unsigned* sc       = (unsigned*)(f0 + o); o += 64;
    unsigned* gHist    = (unsigned*)(f0 + o); o += MAXBINS;
    unsigned* gBase    = (unsigned*)(f0 + o); o += MAXBINS + 1;
    unsigned* gCursor  = (unsigned*)(f0 + o); o += MAXBINS;
    o = (o + 3) & ~(size_t)3;                                     // 16B align
    int4*     recs     = (int4*)(f0 + o);

    size_t need_bytes = (o + 4 * (size_t)E) * sizeof(float);
    const bool sorted_ok = (ws_size >= need_bytes) && (nbins <= MAXBINS) && (E % 4 == 0);

    float* out = (float*)d_out;

    const int Bk = 256;
    const int gN  = (n + Bk - 1) / Bk;
    const int gE  = (E + Bk - 1) / Bk;
    const int gD  = (n + 3) / 4;           // k_dots: 4 waves/block, 1 wave/node
    const int E4  = E / 4;
    const int gE4 = (E4 + Bk - 1) / Bk;

    k_init<<<gN, Bk, 0, stream>>>(NS, stampW, nW, pooled_u, sc, gHist, n);
    k_dots<<<gD, Bk, 0, stream>>>(x, w_l, w_r, xl, xr, n);
    k_ab<<<gN, Bk, 0, stream>>>(xl, xr, pos, w_e, sA, B, sc, n);

    if (sorted_ok) {
        k_hist<<<512, Bk, 0, stream>>>((const int4*)dst, E4, nbins, gHist);
        k_scan<<<1, 64, 0, stream>>>(gHist, gBase, gCursor, nbins, sc, att);
        k_scatter<<<(E + 4095) / 4096, Bk, 0, stream>>>((const int4*)src, (const int4*)dst,
                                                        sA, B, att, sc, gCursor, recs,
                                                        E4, nbins);
        k_binsum<<<nbins, Bk, 0, stream>>>(recs, gBase, bias, logits, sc, n);
    } else {
        k_scan<<<1, 64, 0, stream>>>(gHist, gBase, gCursor, 0, sc, att); // just set M
        k_edge_sum<<<gE, Bk, 0, stream>>>(src, dst, sA, B, att, sc, NS, E);
        k_logits<<<gN, Bk, 0, stream>>>(NS, bias, logits, sc, n);
    }

    k_sumarg<<<gN, Bk, 0, stream>>>(logits, sc, n);
    k_score<<<gN, Bk, 0, stream>>>(logits, sc, out, stamp, n);

    for (int t = 1; t <= 5; ++t) {
        k_bfs_stamp<<<gE4, Bk, 0, stream>>>((const int4*)src, (const int4*)dst, stamp, E4, t);
    }

    k_pool<<<2048, Bk, 0, stream>>>(x, stamp, pooled_u, n);
    k_poolwrite<<<1, Bk, 0, stream>>>(pooled_u, out, n);
}

// Round 5
// 333.822 us; speedup vs baseline: 2.0498x; 1.1167x over previous
//
#include <hip/hip_runtime.h>

#define D_FEAT 256
#define NEG_SLOPE 0.2f
#define MAXBINS 512
#define SENT 0xFFFFFFFFu

// Monotone float -> uint map (order-preserving, includes +-inf)
__device__ __forceinline__ unsigned fmap(float f) {
    unsigned u = __float_as_uint(f);
    return (u & 0x80000000u) ? ~u : (u | 0x80000000u);
}
__device__ __forceinline__ float funmap(unsigned u) {
    return __uint_as_float((u & 0x80000000u) ? (u ^ 0x80000000u) : ~u);
}

// sc layout: [0] gmax_u  [1] gsum(f32)  [2] argmin  [3] M(f32)
//            [4] maxA_u  [5] maxB_u     [6] minA_u  [7] minB_u

__global__ void k_init(float2* NS, unsigned* stampW, int nW, unsigned* pooled_u,
                       unsigned* sc, unsigned* gHist, int n) {
    int i = blockIdx.x * blockDim.x + threadIdx.x;
    if (i < n) NS[i] = make_float2(0.f, 0.f);
    if (i < nW) stampW[i] = 0xFFFFFFFFu;       // stamp bytes = 0xFF (unreached)
    if (i < D_FEAT) pooled_u[i] = 0u;
    if (i < MAXBINS) gHist[i] = 0u;
    if (i == 0) {
        sc[0] = 0u; ((float*)sc)[1] = 0.f; sc[2] = 0xFFFFFFFFu;
        sc[4] = 0u; sc[5] = 0u; sc[6] = 0xFFFFFFFFu; sc[7] = 0xFFFFFFFFu;
    }
}

// One wave per node: xl[i] = x[i,:]·w_l, xr[i] = x[i,:]·w_r
__global__ void k_dots(const float* __restrict__ x, const float* __restrict__ w_l,
                       const float* __restrict__ w_r, float* __restrict__ xl,
                       float* __restrict__ xr, int n) {
    int wave = (int)((blockIdx.x * blockDim.x + threadIdx.x) >> 6);
    int lane = threadIdx.x & 63;
    if (wave >= n) return;
    const float4* xv = (const float4*)(x + (size_t)wave * D_FEAT);
    float4 v = xv[lane];
    float4 a = ((const float4*)w_l)[lane];
    float4 b = ((const float4*)w_r)[lane];
    float sl = v.x * a.x + v.y * a.y + v.z * a.z + v.w * a.w;
    float sr = v.x * b.x + v.y * b.y + v.z * b.z + v.w * b.w;
    #pragma unroll
    for (int o = 32; o; o >>= 1) { sl += __shfl_xor(sl, o); sr += __shfl_xor(sr, o); }
    if (lane == 0) { xl[wave] = sl; xr[wave] = sr; }
}

// Per node: p = pos·w_e ; a = xl - p ; b = xr + p ; global max/min of a,b
__global__ void k_ab(const float* __restrict__ xl, const float* __restrict__ xr,
                     const float* __restrict__ pos, const float* __restrict__ w_e,
                     float2* __restrict__ sA, float* __restrict__ B,
                     unsigned* sc, int n) {
    int i = blockIdx.x * blockDim.x + threadIdx.x;
    float amax, amin, bmax, bmin;
    if (i < n) {
        float p = pos[3 * i] * w_e[0] + pos[3 * i + 1] * w_e[1] + pos[3 * i + 2] * w_e[2];
        float xli = xl[i];
        float a = xli - p;
        float b = xr[i] + p;
        sA[i] = make_float2(a, xli);
        B[i] = b;
        amax = amin = a; bmax = bmin = b;
    } else {
        amax = bmax = -INFINITY; amin = bmin = INFINITY;
    }
    #pragma unroll
    for (int o = 32; o; o >>= 1) {
        amax = fmaxf(amax, __shfl_xor(amax, o));
        bmax = fmaxf(bmax, __shfl_xor(bmax, o));
        amin = fminf(amin, __shfl_xor(amin, o));
        bmin = fminf(bmin, __shfl_xor(bmin, o));
    }
    __shared__ float s4[4][4];
    int w = threadIdx.x >> 6, l = threadIdx.x & 63;
    if (l == 0) { s4[w][0] = amax; s4[w][1] = bmax; s4[w][2] = amin; s4[w][3] = bmin; }
    __syncthreads();
    if (threadIdx.x == 0) {
        float AM = s4[0][0], BM = s4[0][1], Am = s4[0][2], Bm = s4[0][3];
        #pragma unroll
        for (int k = 1; k < 4; ++k) {
            AM = fmaxf(AM, s4[k][0]); BM = fmaxf(BM, s4[k][1]);
            Am = fminf(Am, s4[k][2]); Bm = fminf(Bm, s4[k][3]);
        }
        atomicMax(&sc[4], fmap(AM)); atomicMax(&sc[5], fmap(BM));
        atomicMin(&sc[6], fmap(Am)); atomicMin(&sc[7], fmap(Bm));
    }
}

// ---------------- sorted (bin-scatter) path ----------------

__global__ void k_hist(const int4* __restrict__ dst4, int E4, int nbins,
                       unsigned* __restrict__ gHist) {
    __shared__ unsigned h[MAXBINS];
    for (int b = threadIdx.x; b < nbins; b += blockDim.x) h[b] = 0u;
    __syncthreads();
    int stride = gridDim.x * blockDim.x;
    for (int i = blockIdx.x * blockDim.x + threadIdx.x; i < E4; i += stride) {
        int4 d = dst4[i];
        atomicAdd(&h[d.x >> 8], 1u);
        atomicAdd(&h[d.y >> 8], 1u);
        atomicAdd(&h[d.z >> 8], 1u);
        atomicAdd(&h[d.w >> 8], 1u);
    }
    __syncthreads();
    for (int b = threadIdx.x; b < nbins; b += blockDim.x)
        if (h[b]) atomicAdd(&gHist[b], h[b]);
}

// One block, 64 lanes: wave-parallel scan of padded bin capacities + compute M.
// cap[b] = align16(hist[b] + 15*nBlk) covers worst-case per-block padding.
__global__ void k_scan(const unsigned* __restrict__ gHist, unsigned* __restrict__ gBase,
                       unsigned* __restrict__ gCursor, int nbins, int nBlk,
                       unsigned* sc, const float* __restrict__ att) {
    int lane = threadIdx.x;
    if (lane == 0) {
        float at = att[0];
        float z = (at >= 0.f) ? (funmap(sc[4]) + funmap(sc[5]))
                              : (funmap(sc[6]) + funmap(sc[7]));
        float lz = (z >= 0.f) ? z : NEG_SLOPE * z;
        ((float*)sc)[3] = lz * at;
    }
    unsigned padw = 15u * (unsigned)nBlk;
    unsigned carry = 0;
    for (int b0 = 0; b0 < nbins; b0 += 64) {
        int b = b0 + lane;
        unsigned v = (b < nbins) ? ((gHist[b] + padw + 15u) & ~15u) : 0u;
        unsigned inc = v;
        #pragma unroll
        for (int o = 1; o < 64; o <<= 1) {
            unsigned t = __shfl_up(inc, o);
            if (lane >= o) inc += t;
        }
        unsigned excl = inc - v + carry;
        if (b < nbins) { gBase[b] = excl; gCursor[b] = excl; }
        carry += __shfl(inc, 63);
    }
}

// 512 threads, 8192 edges/block. Loop1: LDS hist. Reserve 16-word-aligned runs.
// Loop2: re-read edges (L2-hot), scatter 4B words  src | (dst&255)<<17.
// Pad runs to 64B with SENT so no cache line is shared between blocks.
__global__ void k_scatter(const int4* __restrict__ src4, const int4* __restrict__ dst4,
                          unsigned* __restrict__ gCursor, unsigned* __restrict__ recs,
                          int E4, int nbins) {
    __shared__ unsigned h[MAXBINS];
    __shared__ unsigned base[MAXBINS];
    for (int b = threadIdx.x; b < nbins; b += 512) h[b] = 0u;
    __syncthreads();
    int b4 = blockIdx.x * 2048;   // int4 index base (8192 edges)
    #pragma unroll
    for (int g = 0; g < 4; ++g) {
        int idx = b4 + g * 512 + threadIdx.x;
        if (idx < E4) {
            int4 d = dst4[idx];
            atomicAdd(&h[d.x >> 8], 1u);
            atomicAdd(&h[d.y >> 8], 1u);
            atomicAdd(&h[d.z >> 8], 1u);
            atomicAdd(&h[d.w >> 8], 1u);
        }
    }
    __syncthreads();
    for (int b = threadIdx.x; b < nbins; b += 512) {
        unsigned c = h[b];
        h[b] = 0u;
        base[b] = c ? atomicAdd(&gCursor[b], (c + 15u) & ~15u) : 0u;
    }
    __syncthreads();
    #pragma unroll
    for (int g = 0; g < 4; ++g) {
        int idx = b4 + g * 512 + threadIdx.x;
        if (idx < E4) {
            int4 sv = src4[idx];
            int4 dv = dst4[idx];
            int ss[4] = { sv.x, sv.y, sv.z, sv.w };
            int dd[4] = { dv.x, dv.y, dv.z, dv.w };
            #pragma unroll
            for (int j = 0; j < 4; ++j) {
                int d_ = dd[j];
                int bin = d_ >> 8;
                unsigned off = atomicAdd(&h[bin], 1u);
                recs[base[bin] + off] = (unsigned)ss[j] | ((unsigned)(d_ & 255) << 17);
            }
        }
    }
    __syncthreads();
    // pad each run to its 16-word reservation
    for (int b = threadIdx.x; b < nbins; b += 512) {
        unsigned c = h[b];
        unsigned pc = (c + 15u) & ~15u;
        for (unsigned k = c; k < pc; ++k) recs[base[b] + k] = SENT;
    }
}

// One block per bin: recompute ex from sA (L2-resident) + B (LDS), accumulate in LDS,
// fused logits + global max.
__global__ void k_binsum(const unsigned* __restrict__ recs, const unsigned* __restrict__ gBase,
                         const unsigned* __restrict__ gCursor,
                         const float2* __restrict__ sA, const float* __restrict__ B,
                         const float* __restrict__ att, const float* __restrict__ bias,
                         float* __restrict__ logits, unsigned* sc, int n) {
    __shared__ float accx[256];
    __shared__ float accy[256];
    __shared__ float Bb[256];
    int b = blockIdx.x;
    int tid = threadIdx.x;
    int node0 = b << 8;
    accx[tid] = 0.f; accy[tid] = 0.f;
    Bb[tid] = (node0 + tid < n) ? B[node0 + tid] : 0.f;
    __syncthreads();
    const float at = att[0];
    const float M = ((const float*)sc)[3];
    unsigned s0 = gBase[b], s1 = gCursor[b];
    for (unsigned i = s0 + tid; i < s1; i += 256u) {
        unsigned w = recs[i];
        if (w == SENT) continue;
        int src = (int)(w & 0x1FFFFu);
        int loc = (int)(w >> 17);
        float2 sa = sA[src];
        float msg = sa.x + Bb[loc];
        float lr = (msg >= 0.f) ? msg : NEG_SLOPE * msg;
        float e = expf(lr * at - M);
        atomicAdd(&accx[loc], e);
        atomicAdd(&accy[loc], e * sa.y);
    }
    __syncthreads();
    int node = node0 + tid;
    float lg = -INFINITY;
    if (node < n) {
        lg = accy[tid] / (accx[tid] + 1e-38f) + bias[0];
        logits[node] = lg;
    }
    unsigned mu = fmap(lg);
    #pragma unroll
    for (int o = 32; o; o >>= 1) { unsigned t = __shfl_xor(mu, o); mu = (t > mu) ? t : mu; }
    __shared__ unsigned wm[4];
    int w_ = tid >> 6, l = tid & 63;
    if (l == 0) wm[w_] = mu;
    __syncthreads();
    if (tid == 0) {
        unsigned m = wm[0];
        #pragma unroll
        for (int k = 1; k < 4; ++k) m = (wm[k] > m) ? wm[k] : m;
        atomicMax(&sc[0], m);
    }
}

// ---------------- fallback (atomic) path ----------------

__global__ void k_edge_sum(const int* __restrict__ src, const int* __restrict__ dst,
                           const float2* __restrict__ sA, const float* __restrict__ B,
                           const float* __restrict__ att, const unsigned* __restrict__ sc,
                           float2* NS, int E) {
    int i = blockIdx.x * blockDim.x + threadIdx.x;
    if (i >= E) return;
    int s = src[i], d = dst[i];
    float2 sa = sA[s];
    float msg = sa.x + B[d];
    float lr = (msg >= 0.f) ? msg : NEG_SLOPE * msg;
    float ex = expf(lr * att[0] - ((const float*)sc)[3]);
    atomicAdd(&NS[d].x, ex);
    atomicAdd(&NS[d].y, ex * sa.y);
}

__global__ void k_logits(const float2* __restrict__ NS, const float* __restrict__ bias,
                         float* __restrict__ logits, unsigned* sc, int n) {
    int i = blockIdx.x * blockDim.x + threadIdx.x;
    unsigned mu = 0u;
    if (i < n) {
        float2 ns = NS[i];
        float lg = ns.y / (ns.x + 1e-38f) + bias[0];
        logits[i] = lg;
        mu = fmap(lg);
    }
    #pragma unroll
    for (int o = 32; o; o >>= 1) { unsigned t = __shfl_xor(mu, o); mu = (t > mu) ? t : mu; }
    if ((threadIdx.x & 63) == 0) atomicMax(&sc[0], mu);
}

// ---------------- tail: global softmax, argmax, BFS, pool ----------------

__global__ void k_sumarg(const float* __restrict__ logits, unsigned* sc, int n) {
    int i = blockIdx.x * blockDim.x + threadIdx.x;
    unsigned gmax_u = sc[0];
    float gmax = funmap(gmax_u);
    float ex = 0.f;
    if (i < n) {
        float lg = logits[i];
        ex = expf(lg - gmax);
        if (fmap(lg) == gmax_u) atomicMin(&sc[2], (unsigned)i);
    }
    #pragma unroll
    for (int o = 32; o; o >>= 1) ex += __shfl_xor(ex, o);
    if ((threadIdx.x & 63) == 0) atomicAdd((float*)&sc[1], ex);
}

// score + seed the BFS stamp at argmax
__global__ void k_score(const float* __restrict__ logits, const unsigned* __restrict__ sc,
                        float* __restrict__ out, unsigned char* stamp, int n) {
    int i = blockIdx.x * blockDim.x + threadIdx.x;
    if (i >= n) return;
    float gmax = funmap(sc[0]);
    float gsum = ((const float*)sc)[1];
    out[i] = expf(logits[i] - gmax) / gsum;
    if (i == (int)sc[2]) stamp[i] = 0;
}

// In-place timestamp BFS pass t. Loads dst4 only if some lane-src is reached
// (stamp array is 100KB -> L2-hot random byte reads).
__global__ void k_bfs_stamp(const int4* __restrict__ src4, const int4* __restrict__ dst4,
                            unsigned char* __restrict__ stamp, int E4, int t) {
    int i = blockIdx.x * blockDim.x + threadIdx.x;
    if (i >= E4) return;
    int4 s = src4[i];
    unsigned char th = (unsigned char)t;
    bool h0 = stamp[s.x] < th;
    bool h1 = stamp[s.y] < th;
    bool h2 = stamp[s.z] < th;
    bool h3 = stamp[s.w] < th;
    if (!(h0 | h1 | h2 | h3)) return;
    int4 d = dst4[i];
    if (h0 && stamp[d.x] > th) stamp[d.x] = th;
    if (h1 && stamp[d.y] > th) stamp[d.y] = th;
    if (h2 && stamp[d.z] > th) stamp[d.z] = th;
    if (h3 && stamp[d.w] > th) stamp[d.w] = th;
}

// 256 threads = 256 columns; block-strided rows; coalesced x reads
__global__ void k_pool(const float* __restrict__ x, const unsigned char* __restrict__ stamp,
                       unsigned* pooled_u, int n) {
    int t = threadIdx.x;
    float local = -INFINITY;
    for (int node = blockIdx.x; node < n; node += gridDim.x) {
        if (stamp[node] != 0xFF) local = fmaxf(local, x[(size_t)node * D_FEAT + t]);
    }
    atomicMax(&pooled_u[t], fmap(local));
}

__global__ void k_poolwrite(const unsigned* __restrict__ pooled_u, float* __restrict__ out, int n) {
    int t = threadIdx.x;
    out[n + t] = funmap(pooled_u[t]);
}

extern "C" void kernel_launch(void* const* d_in, const int* in_sizes, int n_in,
                              void* d_out, int out_size, void* d_ws, size_t ws_size,
                              hipStream_t stream) {
    const float* x    = (const float*)d_in[0];
    const float* pos  = (const float*)d_in[1];
    const float* w_l  = (const float*)d_in[2];
    const float* w_r  = (const float*)d_in[3];
    const float* w_e  = (const float*)d_in[4];
    const float* att  = (const float*)d_in[5];
    const float* bias = (const float*)d_in[6];
    const int*   ei   = (const int*)d_in[7];

    const int n = in_sizes[0] / D_FEAT;     // 100000
    const int E = in_sizes[7] / 2;          // 3200000
    const int* src = ei;
    const int* dst = ei + E;
    const int nbins = (n + 255) >> 8;       // 391
    const int nW = (n + 3) / 4;             // stamp words
    const int nBlkScat = (E + 8191) / 8192; // 391

    float* f0 = (float*)d_ws;
    size_t o = 0;
    float*    xl       = f0 + o; o += (size_t)n;
    float*    xr       = f0 + o; o += (size_t)n;
    float2*   sA       = (float2*)(f0 + o); o += 2 * (size_t)n;
    float*    B        = f0 + o; o += (size_t)n;
    float*    logits   = f0 + o; o += (size_t)n;
    float2*   NS       = (float2*)(f0 + o); o += 2 * (size_t)n;   // fallback only
    unsigned* stampW   = (unsigned*)(f0 + o); o += (size_t)nW;
    unsigned char* stamp = (unsigned char*)stampW;
    unsigned* pooled_u = (unsigned*)(f0 + o); o += 256;
    unsigned* sc       = (unsigned*)(f0 + o); o += 64;
    unsigned* gHist    = (unsigned*)(f0 + o); o += MAXBINS;
    unsigned* gBase    = (unsigned*)(f0 + o); o += MAXBINS;
    unsigned* gCursor  = (unsigned*)(f0 + o); o += MAXBINS;
    o = (o + 15) & ~(size_t)15;                                   // 64B align
    unsigned* recs     = (unsigned*)(f0 + o);

    // capacity: E real words + worst-case padding (15 per block-bin) + per-bin align slack
    size_t capWords = (size_t)E + (size_t)nbins * (15u * (size_t)nBlkScat + 16u);
    size_t need_bytes = (o + capWords) * sizeof(float);
    const bool sorted_ok = (ws_size >= need_bytes) && (nbins <= MAXBINS) &&
                           (E % 4 == 0) && (n <= (1 << 17));

    float* out = (float*)d_out;

    const int Bk = 256;
    const int gN  = (n + Bk - 1) / Bk;
    const int gE  = (E + Bk - 1) / Bk;
    const int gD  = (n + 3) / 4;           // k_dots: 4 waves/block, 1 wave/node
    const int E4  = E / 4;
    const int gE4 = (E4 + Bk - 1) / Bk;

    k_init<<<gN, Bk, 0, stream>>>(NS, stampW, nW, pooled_u, sc, gHist, n);
    k_dots<<<gD, Bk, 0, stream>>>(x, w_l, w_r, xl, xr, n);
    k_ab<<<gN, Bk, 0, stream>>>(xl, xr, pos, w_e, sA, B, sc, n);

    if (sorted_ok) {
        k_hist<<<512, Bk, 0, stream>>>((const int4*)dst, E4, nbins, gHist);
        k_scan<<<1, 64, 0, stream>>>(gHist, gBase, gCursor, nbins, nBlkScat, sc, att);
        k_scatter<<<nBlkScat, 512, 0, stream>>>((const int4*)src, (const int4*)dst,
                                                gCursor, recs, E4, nbins);
        k_binsum<<<nbins, Bk, 0, stream>>>(recs, gBase, gCursor, sA, B, att, bias,
                                           logits, sc, n);
    } else {
        k_scan<<<1, 64, 0, stream>>>(gHist, gBase, gCursor, 0, 0, sc, att); // just set M
        k_edge_sum<<<gE, Bk, 0, stream>>>(src, dst, sA, B, att, sc, NS, E);
        k_logits<<<gN, Bk, 0, stream>>>(NS, bias, logits, sc, n);
    }

    k_sumarg<<<gN, Bk, 0, stream>>>(logits, sc, n);
    k_score<<<gN, Bk, 0, stream>>>(logits, sc, out, stamp, n);

    for (int t = 1; t <= 5; ++t) {
        k_bfs_stamp<<<gE4, Bk, 0, stream>>>((const int4*)src, (const int4*)dst, stamp, E4, t);
    }

    k_pool<<<2048, Bk, 0, stream>>>(x, stamp, pooled_u, n);
    k_poolwrite<<<1, Bk, 0, stream>>>(pooled_u, out, n);
}

// Round 6
// 280.879 us; speedup vs baseline: 2.4362x; 1.1885x over previous
//
#include <hip/hip_runtime.h>

#define D_FEAT 256
#define NEG_SLOPE 0.2f
#define MAXBINS 512
#define SENT 0xFFFFFFFFu

// Monotone float -> uint map (order-preserving, includes +-inf)
__device__ __forceinline__ unsigned fmap(float f) {
    unsigned u = __float_as_uint(f);
    return (u & 0x80000000u) ? ~u : (u | 0x80000000u);
}
__device__ __forceinline__ float funmap(unsigned u) {
    return __uint_as_float((u & 0x80000000u) ? (u ^ 0x80000000u) : ~u);
}

// sc layout: [0] gmax_u  [1] gsum(f32)  [2] argmin  [3] M(f32)
//            [4] maxA_u  [5] maxB_u     [6] minA_u  [7] minB_u

__global__ void k_init(float2* NS, unsigned* stampW, int nW, unsigned* pooled_u,
                       unsigned* sc, unsigned* gHist, int n) {
    int i = blockIdx.x * blockDim.x + threadIdx.x;
    if (i < n) NS[i] = make_float2(0.f, 0.f);
    if (i < nW) stampW[i] = 0xFFFFFFFFu;       // stamp bytes = 0xFF (unreached)
    if (i < D_FEAT) pooled_u[i] = 0u;
    if (i < MAXBINS) gHist[i] = 0u;
    if (i == 0) {
        sc[0] = 0u; ((float*)sc)[1] = 0.f; sc[2] = 0xFFFFFFFFu;
        sc[4] = 0u; sc[5] = 0u; sc[6] = 0xFFFFFFFFu; sc[7] = 0xFFFFFFFFu;
    }
}

// One wave per node: xl[i] = x[i,:]·w_l, xr[i] = x[i,:]·w_r
__global__ void k_dots(const float* __restrict__ x, const float* __restrict__ w_l,
                       const float* __restrict__ w_r, float* __restrict__ xl,
                       float* __restrict__ xr, int n) {
    int wave = (int)((blockIdx.x * blockDim.x + threadIdx.x) >> 6);
    int lane = threadIdx.x & 63;
    if (wave >= n) return;
    const float4* xv = (const float4*)(x + (size_t)wave * D_FEAT);
    float4 v = xv[lane];
    float4 a = ((const float4*)w_l)[lane];
    float4 b = ((const float4*)w_r)[lane];
    float sl = v.x * a.x + v.y * a.y + v.z * a.z + v.w * a.w;
    float sr = v.x * b.x + v.y * b.y + v.z * b.z + v.w * b.w;
    #pragma unroll
    for (int o = 32; o; o >>= 1) { sl += __shfl_xor(sl, o); sr += __shfl_xor(sr, o); }
    if (lane == 0) { xl[wave] = sl; xr[wave] = sr; }
}

// Per node: p = pos·w_e ; a = xl - p ; b = xr + p ; global max/min of a,b
__global__ void k_ab(const float* __restrict__ xl, const float* __restrict__ xr,
                     const float* __restrict__ pos, const float* __restrict__ w_e,
                     float2* __restrict__ sA, float* __restrict__ B,
                     unsigned* sc, int n) {
    int i = blockIdx.x * blockDim.x + threadIdx.x;
    float amax, amin, bmax, bmin;
    if (i < n) {
        float p = pos[3 * i] * w_e[0] + pos[3 * i + 1] * w_e[1] + pos[3 * i + 2] * w_e[2];
        float xli = xl[i];
        float a = xli - p;
        float b = xr[i] + p;
        sA[i] = make_float2(a, xli);
        B[i] = b;
        amax = amin = a; bmax = bmin = b;
    } else {
        amax = bmax = -INFINITY; amin = bmin = INFINITY;
    }
    #pragma unroll
    for (int o = 32; o; o >>= 1) {
        amax = fmaxf(amax, __shfl_xor(amax, o));
        bmax = fmaxf(bmax, __shfl_xor(bmax, o));
        amin = fminf(amin, __shfl_xor(amin, o));
        bmin = fminf(bmin, __shfl_xor(bmin, o));
    }
    __shared__ float s4[4][4];
    int w = threadIdx.x >> 6, l = threadIdx.x & 63;
    if (l == 0) { s4[w][0] = amax; s4[w][1] = bmax; s4[w][2] = amin; s4[w][3] = bmin; }
    __syncthreads();
    if (threadIdx.x == 0) {
        float AM = s4[0][0], BM = s4[0][1], Am = s4[0][2], Bm = s4[0][3];
        #pragma unroll
        for (int k = 1; k < 4; ++k) {
            AM = fmaxf(AM, s4[k][0]); BM = fmaxf(BM, s4[k][1]);
            Am = fminf(Am, s4[k][2]); Bm = fminf(Bm, s4[k][3]);
        }
        atomicMax(&sc[4], fmap(AM)); atomicMax(&sc[5], fmap(BM));
        atomicMin(&sc[6], fmap(Am)); atomicMin(&sc[7], fmap(Bm));
    }
}

// ---------------- sorted (bin-scatter) path ----------------

__global__ void k_hist(const int4* __restrict__ dst4, int E4, int nbins,
                       unsigned* __restrict__ gHist) {
    __shared__ unsigned h[MAXBINS];
    for (int b = threadIdx.x; b < nbins; b += blockDim.x) h[b] = 0u;
    __syncthreads();
    int stride = gridDim.x * blockDim.x;
    for (int i = blockIdx.x * blockDim.x + threadIdx.x; i < E4; i += stride) {
        int4 d = dst4[i];
        atomicAdd(&h[d.x >> 8], 1u);
        atomicAdd(&h[d.y >> 8], 1u);
        atomicAdd(&h[d.z >> 8], 1u);
        atomicAdd(&h[d.w >> 8], 1u);
    }
    __syncthreads();
    for (int b = threadIdx.x; b < nbins; b += blockDim.x)
        if (h[b]) atomicAdd(&gHist[b], h[b]);
}

// One block, 64 lanes: wave-parallel scan of padded bin capacities + compute M.
// cap[b] = align16(hist[b] + 15*nBlk) covers worst-case per-block padding.
__global__ void k_scan(const unsigned* __restrict__ gHist, unsigned* __restrict__ gBase,
                       unsigned* __restrict__ gCursor, int nbins, int nBlk,
                       unsigned* sc, const float* __restrict__ att) {
    int lane = threadIdx.x;
    if (lane == 0) {
        float at = att[0];
        float z = (at >= 0.f) ? (funmap(sc[4]) + funmap(sc[5]))
                              : (funmap(sc[6]) + funmap(sc[7]));
        float lz = (z >= 0.f) ? z : NEG_SLOPE * z;
        ((float*)sc)[3] = lz * at;
    }
    unsigned padw = 15u * (unsigned)nBlk;
    unsigned carry = 0;
    for (int b0 = 0; b0 < nbins; b0 += 64) {
        int b = b0 + lane;
        unsigned v = (b < nbins) ? ((gHist[b] + padw + 15u) & ~15u) : 0u;
        unsigned inc = v;
        #pragma unroll
        for (int o = 1; o < 64; o <<= 1) {
            unsigned t = __shfl_up(inc, o);
            if (lane >= o) inc += t;
        }
        unsigned excl = inc - v + carry;
        if (b < nbins) { gBase[b] = excl; gCursor[b] = excl; }
        carry += __shfl(inc, 63);
    }
}

// 512 threads, 8192 edges/block. Loop1: LDS hist. Reserve 16-word-aligned runs.
// Loop2: re-read edges (L2-hot), scatter 4B words  src | (dst&255)<<17.
// Pad runs to 64B with SENT so no cache line is shared between blocks.
__global__ void k_scatter(const int4* __restrict__ src4, const int4* __restrict__ dst4,
                          unsigned* __restrict__ gCursor, unsigned* __restrict__ recs,
                          int E4, int nbins) {
    __shared__ unsigned h[MAXBINS];
    __shared__ unsigned base[MAXBINS];
    for (int b = threadIdx.x; b < nbins; b += 512) h[b] = 0u;
    __syncthreads();
    int b4 = blockIdx.x * 2048;   // int4 index base (8192 edges)
    #pragma unroll
    for (int g = 0; g < 4; ++g) {
        int idx = b4 + g * 512 + threadIdx.x;
        if (idx < E4) {
            int4 d = dst4[idx];
            atomicAdd(&h[d.x >> 8], 1u);
            atomicAdd(&h[d.y >> 8], 1u);
            atomicAdd(&h[d.z >> 8], 1u);
            atomicAdd(&h[d.w >> 8], 1u);
        }
    }
    __syncthreads();
    for (int b = threadIdx.x; b < nbins; b += 512) {
        unsigned c = h[b];
        h[b] = 0u;
        base[b] = c ? atomicAdd(&gCursor[b], (c + 15u) & ~15u) : 0u;
    }
    __syncthreads();
    #pragma unroll
    for (int g = 0; g < 4; ++g) {
        int idx = b4 + g * 512 + threadIdx.x;
        if (idx < E4) {
            int4 sv = src4[idx];
            int4 dv = dst4[idx];
            int ss[4] = { sv.x, sv.y, sv.z, sv.w };
            int dd[4] = { dv.x, dv.y, dv.z, dv.w };
            #pragma unroll
            for (int j = 0; j < 4; ++j) {
                int d_ = dd[j];
                int bin = d_ >> 8;
                unsigned off = atomicAdd(&h[bin], 1u);
                recs[base[bin] + off] = (unsigned)ss[j] | ((unsigned)(d_ & 255) << 17);
            }
        }
    }
    __syncthreads();
    // pad each run to its 16-word reservation
    for (int b = threadIdx.x; b < nbins; b += 512) {
        unsigned c = h[b];
        unsigned pc = (c + 15u) & ~15u;
        for (unsigned k = c; k < pc; ++k) recs[base[b] + k] = SENT;
    }
}

// One block per bin: recompute ex from sA (L2-resident) + B (LDS), accumulate in LDS,
// fused logits + global max.
__global__ void k_binsum(const unsigned* __restrict__ recs, const unsigned* __restrict__ gBase,
                         const unsigned* __restrict__ gCursor,
                         const float2* __restrict__ sA, const float* __restrict__ B,
                         const float* __restrict__ att, const float* __restrict__ bias,
                         float* __restrict__ logits, unsigned* sc, int n) {
    __shared__ float accx[256];
    __shared__ float accy[256];
    __shared__ float Bb[256];
    int b = blockIdx.x;
    int tid = threadIdx.x;
    int node0 = b << 8;
    accx[tid] = 0.f; accy[tid] = 0.f;
    Bb[tid] = (node0 + tid < n) ? B[node0 + tid] : 0.f;
    __syncthreads();
    const float at = att[0];
    const float M = ((const float*)sc)[3];
    unsigned s0 = gBase[b], s1 = gCursor[b];
    for (unsigned i = s0 + tid; i < s1; i += 256u) {
        unsigned w = recs[i];
        if (w == SENT) continue;
        int src = (int)(w & 0x1FFFFu);
        int loc = (int)(w >> 17);
        float2 sa = sA[src];
        float msg = sa.x + Bb[loc];
        float lr = (msg >= 0.f) ? msg : NEG_SLOPE * msg;
        float e = expf(lr * at - M);
        atomicAdd(&accx[loc], e);
        atomicAdd(&accy[loc], e * sa.y);
    }
    __syncthreads();
    int node = node0 + tid;
    float lg = -INFINITY;
    if (node < n) {
        lg = accy[tid] / (accx[tid] + 1e-38f) + bias[0];
        logits[node] = lg;
    }
    unsigned mu = fmap(lg);
    #pragma unroll
    for (int o = 32; o; o >>= 1) { unsigned t = __shfl_xor(mu, o); mu = (t > mu) ? t : mu; }
    __shared__ unsigned wm[4];
    int w_ = tid >> 6, l = tid & 63;
    if (l == 0) wm[w_] = mu;
    __syncthreads();
    if (tid == 0) {
        unsigned m = wm[0];
        #pragma unroll
        for (int k = 1; k < 4; ++k) m = (wm[k] > m) ? wm[k] : m;
        atomicMax(&sc[0], m);
    }
}

// ---------------- fallback (atomic) path ----------------

__global__ void k_edge_sum(const int* __restrict__ src, const int* __restrict__ dst,
                           const float2* __restrict__ sA, const float* __restrict__ B,
                           const float* __restrict__ att, const unsigned* __restrict__ sc,
                           float2* NS, int E) {
    int i = blockIdx.x * blockDim.x + threadIdx.x;
    if (i >= E) return;
    int s = src[i], d = dst[i];
    float2 sa = sA[s];
    float msg = sa.x + B[d];
    float lr = (msg >= 0.f) ? msg : NEG_SLOPE * msg;
    float ex = expf(lr * att[0] - ((const float*)sc)[3]);
    atomicAdd(&NS[d].x, ex);
    atomicAdd(&NS[d].y, ex * sa.y);
}

__global__ void k_logits(const float2* __restrict__ NS, const float* __restrict__ bias,
                         float* __restrict__ logits, unsigned* sc, int n) {
    int i = blockIdx.x * blockDim.x + threadIdx.x;
    unsigned mu = 0u;
    if (i < n) {
        float2 ns = NS[i];
        float lg = ns.y / (ns.x + 1e-38f) + bias[0];
        logits[i] = lg;
        mu = fmap(lg);
    }
    #pragma unroll
    for (int o = 32; o; o >>= 1) { unsigned t = __shfl_xor(mu, o); mu = (t > mu) ? t : mu; }
    if ((threadIdx.x & 63) == 0) atomicMax(&sc[0], mu);
}

// ---------------- tail: global softmax, argmax, BFS, pool ----------------

__global__ void k_sumarg(const float* __restrict__ logits, unsigned* sc, int n) {
    int i = blockIdx.x * blockDim.x + threadIdx.x;
    unsigned gmax_u = sc[0];
    float gmax = funmap(gmax_u);
    float ex = 0.f;
    if (i < n) {
        float lg = logits[i];
        ex = expf(lg - gmax);
        if (fmap(lg) == gmax_u) atomicMin(&sc[2], (unsigned)i);
    }
    #pragma unroll
    for (int o = 32; o; o >>= 1) ex += __shfl_xor(ex, o);
    if ((threadIdx.x & 63) == 0) atomicAdd((float*)&sc[1], ex);
}

// score + seed the BFS stamp at argmax
__global__ void k_score(const float* __restrict__ logits, const unsigned* __restrict__ sc,
                        float* __restrict__ out, unsigned char* stamp, int n) {
    int i = blockIdx.x * blockDim.x + threadIdx.x;
    if (i >= n) return;
    float gmax = funmap(sc[0]);
    float gsum = ((const float*)sc)[1];
    out[i] = expf(logits[i] - gmax) / gsum;
    if (i == (int)sc[2]) stamp[i] = 0;
}

// In-place timestamp BFS pass t. Loads dst4 only if some lane-src is reached
// (stamp array is 100KB -> L2-hot random byte reads).
__global__ void k_bfs_stamp(const int4* __restrict__ src4, const int4* __restrict__ dst4,
                            unsigned char* __restrict__ stamp, int E4, int t) {
    int i = blockIdx.x * blockDim.x + threadIdx.x;
    if (i >= E4) return;
    int4 s = src4[i];
    unsigned char th = (unsigned char)t;
    bool h0 = stamp[s.x] < th;
    bool h1 = stamp[s.y] < th;
    bool h2 = stamp[s.z] < th;
    bool h3 = stamp[s.w] < th;
    if (!(h0 | h1 | h2 | h3)) return;
    int4 d = dst4[i];
    if (h0 && stamp[d.x] > th) stamp[d.x] = th;
    if (h1 && stamp[d.y] > th) stamp[d.y] = th;
    if (h2 && stamp[d.z] > th) stamp[d.z] = th;
    if (h3 && stamp[d.w] > th) stamp[d.w] = th;
}

// ---------------- two-stage pool ----------------
// Stage 1: 256 thr = (sub-row tid>>6, col-group tid&63); float4 loads (16B/lane);
// wave-uniform stamp check; LDS-reduce 4 sub-rows -> 64 float4 partials per block.
__global__ void k_pool1(const float* __restrict__ x, const unsigned char* __restrict__ stamp,
                        float4* __restrict__ partial, int n) {
    int sub = threadIdx.x >> 6;
    int lane = threadIdx.x & 63;
    float4 m = make_float4(-INFINITY, -INFINITY, -INFINITY, -INFINITY);
    int stride = gridDim.x * 4;
    for (int node = blockIdx.x * 4 + sub; node < n; node += stride) {
        if (stamp[node] != 0xFF) {
            float4 v = ((const float4*)(x + (size_t)node * D_FEAT))[lane];
            m.x = fmaxf(m.x, v.x); m.y = fmaxf(m.y, v.y);
            m.z = fmaxf(m.z, v.z); m.w = fmaxf(m.w, v.w);
        }
    }
    __shared__ float4 red[256];
    red[threadIdx.x] = m;
    __syncthreads();
    if (sub == 0) {
        float4 a = red[lane], b = red[64 + lane], c = red[128 + lane], d = red[192 + lane];
        a.x = fmaxf(fmaxf(a.x, b.x), fmaxf(c.x, d.x));
        a.y = fmaxf(fmaxf(a.y, b.y), fmaxf(c.y, d.y));
        a.z = fmaxf(fmaxf(a.z, b.z), fmaxf(c.z, d.z));
        a.w = fmaxf(fmaxf(a.w, b.w), fmaxf(c.w, d.w));
        partial[(size_t)blockIdx.x * 64 + lane] = a;
    }
}

// Stage 2: reduce nblk1 partial rows; few thousand atomics total.
__global__ void k_pool2(const float4* __restrict__ partial, int nblk1, unsigned* pooled_u) {
    int sub = threadIdx.x >> 6;
    int lane = threadIdx.x & 63;
    int chunk = (nblk1 + gridDim.x - 1) / gridDim.x;
    int b0 = blockIdx.x * chunk;
    int b1 = min(b0 + chunk, nblk1);
    float4 m = make_float4(-INFINITY, -INFINITY, -INFINITY, -INFINITY);
    for (int b = b0 + sub; b < b1; b += 4) {
        float4 v = partial[(size_t)b * 64 + lane];
        m.x = fmaxf(m.x, v.x); m.y = fmaxf(m.y, v.y);
        m.z = fmaxf(m.z, v.z); m.w = fmaxf(m.w, v.w);
    }
    __shared__ float4 red[256];
    red[threadIdx.x] = m;
    __syncthreads();
    if (sub == 0) {
        float4 a = red[lane], b = red[64 + lane], c = red[128 + lane], d = red[192 + lane];
        a.x = fmaxf(fmaxf(a.x, b.x), fmaxf(c.x, d.x));
        a.y = fmaxf(fmaxf(a.y, b.y), fmaxf(c.y, d.y));
        a.z = fmaxf(fmaxf(a.z, b.z), fmaxf(c.z, d.z));
        a.w = fmaxf(fmaxf(a.w, b.w), fmaxf(c.w, d.w));
        atomicMax(&pooled_u[lane * 4 + 0], fmap(a.x));
        atomicMax(&pooled_u[lane * 4 + 1], fmap(a.y));
        atomicMax(&pooled_u[lane * 4 + 2], fmap(a.z));
        atomicMax(&pooled_u[lane * 4 + 3], fmap(a.w));
    }
}

__global__ void k_poolwrite(const unsigned* __restrict__ pooled_u, float* __restrict__ out, int n) {
    int t = threadIdx.x;
    out[n + t] = funmap(pooled_u[t]);
}

extern "C" void kernel_launch(void* const* d_in, const int* in_sizes, int n_in,
                              void* d_out, int out_size, void* d_ws, size_t ws_size,
                              hipStream_t stream) {
    const float* x    = (const float*)d_in[0];
    const float* pos  = (const float*)d_in[1];
    const float* w_l  = (const float*)d_in[2];
    const float* w_r  = (const float*)d_in[3];
    const float* w_e  = (const float*)d_in[4];
    const float* att  = (const float*)d_in[5];
    const float* bias = (const float*)d_in[6];
    const int*   ei   = (const int*)d_in[7];

    const int n = in_sizes[0] / D_FEAT;     // 100000
    const int E = in_sizes[7] / 2;          // 3200000
    const int* src = ei;
    const int* dst = ei + E;
    const int nbins = (n + 255) >> 8;       // 391
    const int nW = (n + 3) / 4;             // stamp words
    const int nBlkScat = (E + 8191) / 8192; // 391

    float* f0 = (float*)d_ws;
    size_t o = 0;
    float*    xl       = f0 + o; o += (size_t)n;
    float*    xr       = f0 + o; o += (size_t)n;
    float2*   sA       = (float2*)(f0 + o); o += 2 * (size_t)n;
    float*    B        = f0 + o; o += (size_t)n;
    float*    logits   = f0 + o; o += (size_t)n;
    o = (o + 3) & ~(size_t)3;                                     // 16B align for partial
    float2*   NS       = (float2*)(f0 + o); o += 2 * (size_t)n;   // fallback / pool partials
    float4*   partial  = (float4*)NS;                             // NS dead by pool time
    unsigned* stampW   = (unsigned*)(f0 + o); o += (size_t)nW;
    unsigned char* stamp = (unsigned char*)stampW;
    unsigned* pooled_u = (unsigned*)(f0 + o); o += 256;
    unsigned* sc       = (unsigned*)(f0 + o); o += 64;
    unsigned* gHist    = (unsigned*)(f0 + o); o += MAXBINS;
    unsigned* gBase    = (unsigned*)(f0 + o); o += MAXBINS;
    unsigned* gCursor  = (unsigned*)(f0 + o); o += MAXBINS;
    o = (o + 15) & ~(size_t)15;                                   // 64B align
    unsigned* recs     = (unsigned*)(f0 + o);

    // pool stage-1 blocks: partials must fit in NS region (2n floats)
    int nblk1 = (int)((2 * (size_t)n) / 256);
    if (nblk1 > 768) nblk1 = 768;
    if (nblk1 < 1) nblk1 = 1;

    // capacity: E real words + worst-case padding (15 per block-bin) + per-bin align slack
    size_t capWords = (size_t)E + (size_t)nbins * (15u * (size_t)nBlkScat + 16u);
    size_t need_bytes = (o + capWords) * sizeof(float);
    const bool sorted_ok = (ws_size >= need_bytes) && (nbins <= MAXBINS) &&
                           (E % 4 == 0) && (n <= (1 << 17));

    float* out = (float*)d_out;

    const int Bk = 256;
    const int gN  = (n + Bk - 1) / Bk;
    const int gE  = (E + Bk - 1) / Bk;
    const int gD  = (n + 3) / 4;           // k_dots: 4 waves/block, 1 wave/node
    const int E4  = E / 4;
    const int gE4 = (E4 + Bk - 1) / Bk;

    k_init<<<gN, Bk, 0, stream>>>(NS, stampW, nW, pooled_u, sc, gHist, n);
    k_dots<<<gD, Bk, 0, stream>>>(x, w_l, w_r, xl, xr, n);
    k_ab<<<gN, Bk, 0, stream>>>(xl, xr, pos, w_e, sA, B, sc, n);

    if (sorted_ok) {
        k_hist<<<512, Bk, 0, stream>>>((const int4*)dst, E4, nbins, gHist);
        k_scan<<<1, 64, 0, stream>>>(gHist, gBase, gCursor, nbins, nBlkScat, sc, att);
        k_scatter<<<nBlkScat, 512, 0, stream>>>((const int4*)src, (const int4*)dst,
                                                gCursor, recs, E4, nbins);
        k_binsum<<<nbins, Bk, 0, stream>>>(recs, gBase, gCursor, sA, B, att, bias,
                                           logits, sc, n);
    } else {
        k_scan<<<1, 64, 0, stream>>>(gHist, gBase, gCursor, 0, 0, sc, att); // just set M
        k_edge_sum<<<gE, Bk, 0, stream>>>(src, dst, sA, B, att, sc, NS, E);
        k_logits<<<gN, Bk, 0, stream>>>(NS, bias, logits, sc, n);
    }

    k_sumarg<<<gN, Bk, 0, stream>>>(logits, sc, n);
    k_score<<<gN, Bk, 0, stream>>>(logits, sc, out, stamp, n);

    for (int t = 1; t <= 5; ++t) {
        k_bfs_stamp<<<gE4, Bk, 0, stream>>>((const int4*)src, (const int4*)dst, stamp, E4, t);
    }

    k_pool1<<<nblk1, Bk, 0, stream>>>(x, stamp, partial, n);
    k_pool2<<<16, Bk, 0, stream>>>(partial, nblk1, pooled_u);
    k_poolwrite<<<1, Bk, 0, stream>>>(pooled_u, out, n);
}